// Round 4
// baseline (256.510 us; speedup 1.0000x reference)
//
#include <hip/hip_runtime.h>

#define NB 4
#define C  256
#define NN 4096

typedef _Float16 half8   __attribute__((ext_vector_type(8)));
typedef _Float16 half4_t __attribute__((ext_vector_type(4)));
typedef _Float16 h2      __attribute__((ext_vector_type(2)));
typedef float    f32x4   __attribute__((ext_vector_type(4)));
typedef float    f32x16  __attribute__((ext_vector_type(16)));

static __device__ __forceinline__ f32x4 mfma16(half8 a, half8 b, f32x4 c) {
    return __builtin_amdgcn_mfma_f32_16x16x32_f16(a, b, c, 0, 0, 0);
}
static __device__ __forceinline__ f32x16 mfma32(half8 a, half8 b, f32x16 c) {
    return __builtin_amdgcn_mfma_f32_32x32x16_f16(a, b, c, 0, 0, 0);
}
static __device__ __forceinline__ void gld16(const void* g, void* l) {
    __builtin_amdgcn_global_load_lds(
        (const __attribute__((address_space(1))) unsigned int*)g,
        (__attribute__((address_space(3))) unsigned int*)l, 16, 0, 0);
}
static __device__ __forceinline__ h2 cvtpk(float a, float b) {
    auto r = __builtin_amdgcn_cvt_pkrtz(a, b);   // __fp16 ext_vector(2)
    return *reinterpret_cast<h2*>(&r);           // same bits, h2 type
}

// ---------------------------------------------------------------------------
// Kernel 1: QKV projection (single-f16) + relu(fea) copy to out.
//   Qt[b][n][t], Kt[b][n][t]  (N x 256, t contiguous)  f16
//   Vp[b][o][n]               (256 x N, n contiguous)  f16
// ---------------------------------------------------------------------------
__global__ __launch_bounds__(256) void proj_kernel(
    const float* __restrict__ fea, const float* __restrict__ Wq,
    const float* __restrict__ Wk, const float* __restrict__ Wv,
    _Float16* __restrict__ Qt, _Float16* __restrict__ Kt,
    _Float16* __restrict__ Vp, float* __restrict__ out)
{
    const int lin = blockIdx.x + gridDim.x * blockIdx.y;
    const int xcd = lin & 7;
    const int b   = xcd >> 1;
    const int nt  = ((lin >> 3) << 1) | (xcd & 1);
    const int n0  = nt * 32;

    __shared__ __align__(16) _Float16 fh[32][264];

    const int tid = threadIdx.x;
    {
        const int nl = tid & 31, rr = tid >> 5;
        const float* feab = fea + (size_t)b * C * NN + n0 + nl;
        float* outb = out + (size_t)b * 2 * C * NN + (size_t)C * NN + n0 + nl;
#pragma unroll
        for (int p = 0; p < 32; ++p) {
            const int i = p * 8 + rr;
            const float v = feab[(size_t)i * NN];
            outb[(size_t)i * NN] = fmaxf(v, 0.f);
            fh[nl][i] = (_Float16)v;
        }
    }
    __syncthreads();

    const int w = tid >> 6, lane = tid & 63, lr = lane & 15, lg = lane >> 4;

    const float* const Ws[2] = {Wq, Wk};
    _Float16* const   Od[2] = {Qt + (size_t)b * NN * C, Kt + (size_t)b * NN * C};
#pragma unroll 1
    for (int qk = 0; qk < 2; ++qk) {
        const float* __restrict__ W = Ws[qk];
        f32x4 acc[2][4];
#pragma unroll
        for (int mi = 0; mi < 2; ++mi)
#pragma unroll
            for (int ni = 0; ni < 4; ++ni) acc[mi][ni] = (f32x4){0.f, 0.f, 0.f, 0.f};

#pragma unroll 1
        for (int kt = 0; kt < 8; ++kt) {
            half8 ah[2];
#pragma unroll
            for (int mi = 0; mi < 2; ++mi)
                ah[mi] = *(const half8*)&fh[mi * 16 + lr][kt * 32 + lg * 8];
            half8 bh[4];
#pragma unroll
            for (int ni = 0; ni < 4; ++ni) {
                const float* src = W + (size_t)(w * 64 + ni * 16 + lr) * C + kt * 32 + lg * 8;
                const float4 x0 = *(const float4*)src;
                const float4 x1 = *(const float4*)(src + 4);
                bh[ni][0] = (_Float16)x0.x; bh[ni][1] = (_Float16)x0.y;
                bh[ni][2] = (_Float16)x0.z; bh[ni][3] = (_Float16)x0.w;
                bh[ni][4] = (_Float16)x1.x; bh[ni][5] = (_Float16)x1.y;
                bh[ni][6] = (_Float16)x1.z; bh[ni][7] = (_Float16)x1.w;
            }
#pragma unroll
            for (int mi = 0; mi < 2; ++mi)
#pragma unroll
                for (int ni = 0; ni < 4; ++ni)
                    acc[mi][ni] = mfma16(ah[mi], bh[ni], acc[mi][ni]);
        }
        _Float16* dst = Od[qk];
#pragma unroll
        for (int mi = 0; mi < 2; ++mi)
#pragma unroll
            for (int ni = 0; ni < 4; ++ni)
#pragma unroll
                for (int r = 0; r < 4; ++r)
                    dst[(size_t)(n0 + mi * 16 + lg * 4 + r) * C + (w * 64 + ni * 16 + lr)] =
                        (_Float16)acc[mi][ni][r];
    }

    {
        f32x4 acc[4][2];
#pragma unroll
        for (int mi = 0; mi < 4; ++mi)
#pragma unroll
            for (int ni = 0; ni < 2; ++ni) acc[mi][ni] = (f32x4){0.f, 0.f, 0.f, 0.f};

#pragma unroll 1
        for (int kt = 0; kt < 8; ++kt) {
            half8 ah[4];
#pragma unroll
            for (int mi = 0; mi < 4; ++mi) {
                const float* src = Wv + (size_t)(w * 64 + mi * 16 + lr) * C + kt * 32 + lg * 8;
                const float4 x0 = *(const float4*)src;
                const float4 x1 = *(const float4*)(src + 4);
                ah[mi][0] = (_Float16)x0.x; ah[mi][1] = (_Float16)x0.y;
                ah[mi][2] = (_Float16)x0.z; ah[mi][3] = (_Float16)x0.w;
                ah[mi][4] = (_Float16)x1.x; ah[mi][5] = (_Float16)x1.y;
                ah[mi][6] = (_Float16)x1.z; ah[mi][7] = (_Float16)x1.w;
            }
            half8 bh[2];
#pragma unroll
            for (int ni = 0; ni < 2; ++ni)
                bh[ni] = *(const half8*)&fh[ni * 16 + lr][kt * 32 + lg * 8];
#pragma unroll
            for (int mi = 0; mi < 4; ++mi)
#pragma unroll
                for (int ni = 0; ni < 2; ++ni)
                    acc[mi][ni] = mfma16(ah[mi], bh[ni], acc[mi][ni]);
        }
        _Float16* vb = Vp + (size_t)b * C * NN;
#pragma unroll
        for (int mi = 0; mi < 4; ++mi)
#pragma unroll
            for (int ni = 0; ni < 2; ++ni)
#pragma unroll
                for (int r = 0; r < 4; ++r)
                    vb[(size_t)(w * 64 + mi * 16 + lg * 4 + r) * NN + n0 + ni * 16 + lr] =
                        (_Float16)acc[mi][ni][r];
    }
}

// ---------------------------------------------------------------------------
// Kernel 2: split-K flash attention, j_wave=64, o-split wave pairs, i_tile=64.
// 8 waves (2 o/i-halves x 4 j-groups). K single-buffer, V double-buffer,
// staged via global_load_lds with pre-swizzled sources. O master in f16.
// Raw (non-vmcnt-draining) barrier before PV keeps prefetch in flight.
// ---------------------------------------------------------------------------
template<int KS>
__global__ __launch_bounds__(512, 2) void attn2(
    const _Float16* __restrict__ Qt, const _Float16* __restrict__ Kt,
    const _Float16* __restrict__ Vp, _Float16* __restrict__ Opart,
    float* __restrict__ ml, float* __restrict__ out)
{
    extern __shared__ char smem[];
    char* Ksh = smem;                                   // [64][256] f16, 512B rows
    char* Vsh0 = smem + 32768;                          // [256][64] f16, 128B rows
    char* Vsh1 = smem + 65536;
    char* Psh = smem + 98304;                           // [4][64][64] f16, 128B rows
    float* stats = (float*)(smem + 131072);             // [4][2][64]

    const int lin = blockIdx.x;
    const int xcd = lin & 7, slot = lin >> 3;
    int b, ksid, jt;
    if constexpr (KS == 4) { b = xcd >> 1; ksid = ((xcd & 1) << 1) | (slot >> 4); jt = slot & 15; }
    else                   { b = xcd >> 1; ksid = 0; jt = (slot << 1) | (xcd & 1); }

    const int tid = threadIdx.x;
    const int w = tid >> 6, lane = tid & 63;
    const int g = w >> 2, jg = w & 3;
    const int l31 = lane & 31, hi = lane >> 5, lr = lane & 15, lg = lane >> 4;
    const int j0 = jt * 256 + jg * 64;
    const int iBase = ksid * (NN / KS);
    const int T = (NN / KS) / 64;

    const _Float16* Qb = Qt + (size_t)b * NN * C;
    const char* KbC = (const char*)(Kt + (size_t)b * NN * C);
    const char* VbC = (const char*)(Vp + (size_t)b * C * NN);

    const int swzA = (l31 & 7) << 4;   // K-read / P-write rows (row&7 == l31&7)
    const int swzB = (lr & 7) << 4;    // V-read / P-read rows  (row&7 == lr&7)

    // Q fragments: 64 j-cols x C, resident (128 VGPR)
    half8 q[2][16];
#pragma unroll
    for (int jf = 0; jf < 2; ++jf)
#pragma unroll
        for (int kk = 0; kk < 16; ++kk)
            q[jf][kk] = *(const half8*)(Qb + (size_t)(j0 + jf * 32 + l31) * C + kk * 16 + hi * 8);

    // O master in f16: [of 8][jf16 4][pair 2]
    h2 Om[8][4][2];
#pragma unroll
    for (int of = 0; of < 8; ++of)
#pragma unroll
        for (int c = 0; c < 4; ++c) { Om[of][c][0] = (h2){0, 0}; Om[of][c][1] = (h2){0, 0}; }
    float mrq[2] = {-1e30f, -1e30f};
    float mrp[4] = {-1e30f, -1e30f, -1e30f, -1e30f};
    float ll[2] = {0.f, 0.f};

#define STAGE(dstV, t_) do {                                                   \
    const int i0_ = iBase + (t_) * 64;                                         \
    const char* ksg_ = KbC + (size_t)i0_ * 512;                                \
    _Pragma("unroll")                                                          \
    for (int r_ = 0; r_ < 4; ++r_) {                                           \
        const int p_ = r_ * 8192 + tid * 16;                                   \
        const int row_ = p_ >> 9, col_ = p_ & 511;                             \
        gld16(ksg_ + (size_t)row_ * 512 + (col_ ^ ((row_ & 7) << 4)), Ksh + p_); \
    }                                                                          \
    _Pragma("unroll")                                                          \
    for (int r_ = 0; r_ < 4; ++r_) {                                           \
        const int p_ = r_ * 8192 + tid * 16;                                   \
        const int row_ = p_ >> 7, col_ = p_ & 127;                             \
        gld16(VbC + (size_t)row_ * 8192 + (size_t)i0_ * 2 + (col_ ^ ((row_ & 7) << 4)), (dstV) + p_); \
    }                                                                          \
} while (0)

    STAGE(Vsh0, 0);

#pragma unroll 1
    for (int t = 0; t < T; ++t) {
        __syncthreads();   // A: drains vmcnt -> K(t), V(t) staged and visible

        // ---- QK^T: S[i-half(g) 32, j 64] with mfma32
        f32x16 s[2];
        s[0] = (f32x16)(0.f); s[1] = (f32x16)(0.f);
        const char* krow = Ksh + (size_t)(g * 32 + l31) * 512;
#pragma unroll
        for (int kk = 0; kk < 16; ++kk) {
            const half8 a = *(const half8*)(krow + ((kk * 32 + hi * 16) ^ swzA));
            s[0] = mfma32(a, q[0][kk], s[0]);
            s[1] = mfma32(a, q[1][kk], s[1]);
        }

        // ---- per-j half-max -> stats
#pragma unroll
        for (int jf = 0; jf < 2; ++jf) {
            float mh = s[jf][0];
#pragma unroll
            for (int r = 1; r < 16; ++r) mh = fmaxf(mh, s[jf][r]);
            mh = fmaxf(mh, __shfl_xor(mh, 32, 64));
            if (hi == 0) stats[(jg * 2 + g) * 64 + jf * 32 + l31] = mh;
        }
        __syncthreads();   // B: QK reads done; stats visible. vmcnt==0 here.

        if (t + 1 < T) {
            if ((t + 1) & 1) STAGE(Vsh1, t + 1); else STAGE(Vsh0, t + 1);
        }

        // ---- combine halves, unconditional rescale (P <= 1)
        float scq[2];
#pragma unroll
        for (int jf = 0; jf < 2; ++jf) {
            const int j = jf * 32 + l31;
            const float mt = fmaxf(stats[(jg * 2 + 0) * 64 + j], stats[(jg * 2 + 1) * 64 + j]);
            const float mn = fmaxf(mrq[jf], mt);
            scq[jf] = __expf(mrq[jf] - mn);
            mrq[jf] = mn;
            ll[jf] *= scq[jf];
        }
#pragma unroll
        for (int c = 0; c < 4; ++c) {
            const int j = c * 16 + lr;
            const float mt = fmaxf(stats[(jg * 2 + 0) * 64 + j], stats[(jg * 2 + 1) * 64 + j]);
            const float mn = fmaxf(mrp[c], mt);
            const float sc = __expf(mrp[c] - mn);
            mrp[c] = mn;
            const h2 s2 = {(_Float16)sc, (_Float16)sc};
#pragma unroll
            for (int of = 0; of < 8; ++of) { Om[of][c][0] *= s2; Om[of][c][1] *= s2; }
        }

        // ---- P = exp(S - m) -> Ps (f16), accumulate l
        char* pw = Psh + jg * 8192;
#pragma unroll
        for (int jf = 0; jf < 2; ++jf) {
            const int jl = jf * 32 + l31;
            float lsum = 0.f;
#pragma unroll
            for (int qc = 0; qc < 4; ++qc) {
                half4_t ph;
#pragma unroll
                for (int r = 0; r < 4; ++r) {
                    const float p = __expf(s[jf][qc * 4 + r] - mrq[jf]);
                    lsum += p;
                    ph[r] = (_Float16)p;
                }
                *(half4_t*)(pw + (size_t)jl * 128 + ((qc * 16 + hi * 8 + g * 64) ^ swzA)) = ph;
            }
            ll[jf] += lsum;
        }

        // C: raw barrier — waits LDS writes only, leaves gld16 prefetch in flight
        asm volatile("s_waitcnt lgkmcnt(0)\n\ts_barrier" ::: "memory");
        __builtin_amdgcn_sched_barrier(0);

        // ---- PV: O[o-half(g) 128, j 64] += V P  (mfma16, k=32)
        const char* vB = ((t & 1) ? Vsh1 : Vsh0);
        const char* pr = Psh + jg * 8192;
#pragma unroll
        for (int kk = 0; kk < 2; ++kk) {
            half8 pb[4];
#pragma unroll
            for (int c = 0; c < 4; ++c)
                pb[c] = *(const half8*)(pr + (size_t)(c * 16 + lr) * 128 + ((kk * 64 + lg * 16) ^ swzB));
#pragma unroll
            for (int of = 0; of < 8; ++of) {
                const int vrow = g * 128 + of * 16 + lr;
                const half8 va = *(const half8*)(vB + (size_t)vrow * 128 + ((kk * 64 + lg * 16) ^ swzB));
#pragma unroll
                for (int c = 0; c < 4; ++c) {
                    f32x4 acc = (f32x4){0.f, 0.f, 0.f, 0.f};
                    acc = mfma16(va, pb[c], acc);
                    Om[of][c][0] += cvtpk(acc[0], acc[1]);
                    Om[of][c][1] += cvtpk(acc[2], acc[3]);
                }
            }
        }
    }

    // ---- epilogue: l exchange, normalize, write
    __syncthreads();
#pragma unroll
    for (int jf = 0; jf < 2; ++jf) {
        float lt = ll[jf] + __shfl_xor(ll[jf], 32, 64);
        if (hi == 0) stats[(jg * 2 + g) * 64 + jf * 32 + l31] = lt;
    }
    __syncthreads();

    float il[4];
#pragma unroll
    for (int c = 0; c < 4; ++c) {
        const int j = c * 16 + lr;
        const float L = stats[(jg * 2 + 0) * 64 + j] + stats[(jg * 2 + 1) * 64 + j];
        il[c] = 1.f / L;
    }

    if constexpr (KS == 4) {
        if (g == 0 && hi == 0) {
            float* mlb = ml + (size_t)(b * KS + ksid) * 2 * NN;
#pragma unroll
            for (int jf = 0; jf < 2; ++jf) {
                const int j = jf * 32 + l31;
                const float L = stats[(jg * 2 + 0) * 64 + j] + stats[(jg * 2 + 1) * 64 + j];
                mlb[j0 + j] = mrq[jf];
                mlb[NN + j0 + j] = L;
            }
        }
        _Float16* op = Opart + (size_t)(b * KS + ksid) * C * NN;
#pragma unroll
        for (int of = 0; of < 8; ++of)
#pragma unroll
            for (int c = 0; c < 4; ++c) {
                const int o0 = g * 128 + of * 16 + lg * 4;
                const int j = j0 + c * 16 + lr;
                const h2 ih = {(_Float16)il[c], (_Float16)il[c]};
                const h2 v0 = Om[of][c][0] * ih;
                const h2 v1 = Om[of][c][1] * ih;
                op[(size_t)(o0 + 0) * NN + j] = v0[0];
                op[(size_t)(o0 + 1) * NN + j] = v0[1];
                op[(size_t)(o0 + 2) * NN + j] = v1[0];
                op[(size_t)(o0 + 3) * NN + j] = v1[1];
            }
    } else {
        float* ob = out + (size_t)b * 2 * C * NN;
#pragma unroll
        for (int of = 0; of < 8; ++of)
#pragma unroll
            for (int c = 0; c < 4; ++c) {
                const int o0 = g * 128 + of * 16 + lg * 4;
                const int j = j0 + c * 16 + lr;
                ob[(size_t)(o0 + 0) * NN + j] = fmaxf((float)Om[of][c][0][0] * il[c], 0.f);
                ob[(size_t)(o0 + 1) * NN + j] = fmaxf((float)Om[of][c][0][1] * il[c], 0.f);
                ob[(size_t)(o0 + 2) * NN + j] = fmaxf((float)Om[of][c][1][0] * il[c], 0.f);
                ob[(size_t)(o0 + 3) * NN + j] = fmaxf((float)Om[of][c][1][1] * il[c], 0.f);
            }
    }
#undef STAGE
}

// ---------------------------------------------------------------------------
// Kernel 3: combine split-K partials.
// ---------------------------------------------------------------------------
template<int KS>
__global__ __launch_bounds__(256) void combine_kernel(
    const _Float16* __restrict__ Opart, const float* __restrict__ ml,
    float* __restrict__ out)
{
    const int b = blockIdx.x >> 6, cc = blockIdx.x & 63;
    const int tid = threadIdx.x;
    const int col = cc * 64 + (tid & 63);
    const int op0 = tid >> 6;
    float mv[KS], wgt[KS];
    float M = -1e30f;
#pragma unroll
    for (int s = 0; s < KS; ++s) {
        mv[s] = ml[(size_t)(b * KS + s) * 2 * NN + col];
        M = fmaxf(M, mv[s]);
    }
    float L = 0.f;
#pragma unroll
    for (int s = 0; s < KS; ++s) {
        const float lv = ml[((size_t)(b * KS + s) * 2 + 1) * NN + col];
        wgt[s] = __expf(mv[s] - M) * lv; L += wgt[s];
    }
    const float invL = 1.f / L;
#pragma unroll
    for (int s = 0; s < KS; ++s) wgt[s] *= invL;
    float* ob = out + (size_t)b * 2 * C * NN + col;
    for (int oit = 0; oit < 64; ++oit) {
        const int o = oit * 4 + op0;
        float acc = 0.f;
#pragma unroll
        for (int s = 0; s < KS; ++s)
            acc += wgt[s] * (float)Opart[((size_t)(b * KS + s) * C + o) * NN + col];
        ob[(size_t)o * NN] = fmaxf(acc, 0.f);
    }
}

// ---------------------------------------------------------------------------
extern "C" void kernel_launch(void* const* d_in, const int* in_sizes, int n_in,
                              void* d_out, int out_size, void* d_ws, size_t ws_size,
                              hipStream_t stream) {
    const float* fea = (const float*)d_in[0];
    const float* Wq  = (const float*)d_in[1];
    const float* Wk  = (const float*)d_in[2];
    const float* Wv  = (const float*)d_in[3];
    float* out = (float*)d_out;

    _Float16* Qt = (_Float16*)d_ws;
    _Float16* Kt = Qt + (size_t)NB * NN * C;
    _Float16* Vp = Kt + (size_t)NB * NN * C;
    char* extra = (char*)(Vp + (size_t)NB * NN * C);
    const size_t base = (size_t)3 * NB * NN * C * sizeof(_Float16);

    proj_kernel<<<dim3(128, 4), 256, 0, stream>>>(fea, Wq, Wk, Wv, Qt, Kt, Vp, out);

    const int SMEM = 131072 + 2048;
    const size_t need4 = base + (size_t)4 * NB * C * NN * 2 + (size_t)4 * NB * 2 * NN * 4;

    if (ws_size >= need4) {
        _Float16* Op = (_Float16*)extra;
        float* mlp = (float*)(extra + (size_t)4 * NB * C * NN * 2);
        (void)hipFuncSetAttribute(reinterpret_cast<const void*>(&attn2<4>),
                                  hipFuncAttributeMaxDynamicSharedMemorySize, SMEM);
        attn2<4><<<256, 512, SMEM, stream>>>(Qt, Kt, Vp, Op, mlp, out);
        combine_kernel<4><<<NB * 64, 256, 0, stream>>>(Op, mlp, out);
    } else {
        (void)hipFuncSetAttribute(reinterpret_cast<const void*>(&attn2<1>),
                                  hipFuncAttributeMaxDynamicSharedMemorySize, SMEM);
        attn2<1><<<64, 512, SMEM, stream>>>(Qt, Kt, Vp, nullptr, nullptr, out);
    }
}

// Round 5
// 216.156 us; speedup vs baseline: 1.1867x; 1.1867x over previous
//
#include <hip/hip_runtime.h>

#define NB 4
#define C  256
#define NN 4096

typedef _Float16 half8   __attribute__((ext_vector_type(8)));
typedef _Float16 half4_t __attribute__((ext_vector_type(4)));
typedef _Float16 h2      __attribute__((ext_vector_type(2)));
typedef float    f32x4   __attribute__((ext_vector_type(4)));
typedef float    f32x16  __attribute__((ext_vector_type(16)));

static __device__ __forceinline__ f32x4 mfma16(half8 a, half8 b, f32x4 c) {
    return __builtin_amdgcn_mfma_f32_16x16x32_f16(a, b, c, 0, 0, 0);
}
static __device__ __forceinline__ f32x16 mfma32(half8 a, half8 b, f32x16 c) {
    return __builtin_amdgcn_mfma_f32_32x32x16_f16(a, b, c, 0, 0, 0);
}
static __device__ __forceinline__ void gld16(const void* g, void* l) {
    __builtin_amdgcn_global_load_lds(
        (const __attribute__((address_space(1))) unsigned int*)g,
        (__attribute__((address_space(3))) unsigned int*)l, 16, 0, 0);
}
static __device__ __forceinline__ h2 cvtpk(float a, float b) {
    auto r = __builtin_amdgcn_cvt_pkrtz(a, b);   // __fp16 ext_vector(2)
    return *reinterpret_cast<h2*>(&r);           // same bits, h2 type
}

// ---------------------------------------------------------------------------
// Kernel 1: QKV projection (single-f16) + relu(fea) copy to out.
//   Qt[b][n][t], Kt[b][n][t]  (N x 256, t contiguous)  f16
//   Vp[b][o][n]               (256 x N, n contiguous)  f16
// ---------------------------------------------------------------------------
__global__ __launch_bounds__(256) void proj_kernel(
    const float* __restrict__ fea, const float* __restrict__ Wq,
    const float* __restrict__ Wk, const float* __restrict__ Wv,
    _Float16* __restrict__ Qt, _Float16* __restrict__ Kt,
    _Float16* __restrict__ Vp, float* __restrict__ out)
{
    const int lin = blockIdx.x + gridDim.x * blockIdx.y;
    const int xcd = lin & 7;
    const int b   = xcd >> 1;
    const int nt  = ((lin >> 3) << 1) | (xcd & 1);
    const int n0  = nt * 32;

    __shared__ __align__(16) _Float16 fh[32][264];

    const int tid = threadIdx.x;
    {
        const int nl = tid & 31, rr = tid >> 5;
        const float* feab = fea + (size_t)b * C * NN + n0 + nl;
        float* outb = out + (size_t)b * 2 * C * NN + (size_t)C * NN + n0 + nl;
#pragma unroll
        for (int p = 0; p < 32; ++p) {
            const int i = p * 8 + rr;
            const float v = feab[(size_t)i * NN];
            outb[(size_t)i * NN] = fmaxf(v, 0.f);
            fh[nl][i] = (_Float16)v;
        }
    }
    __syncthreads();

    const int w = tid >> 6, lane = tid & 63, lr = lane & 15, lg = lane >> 4;

    const float* const Ws[2] = {Wq, Wk};
    _Float16* const   Od[2] = {Qt + (size_t)b * NN * C, Kt + (size_t)b * NN * C};
#pragma unroll 1
    for (int qk = 0; qk < 2; ++qk) {
        const float* __restrict__ W = Ws[qk];
        f32x4 acc[2][4];
#pragma unroll
        for (int mi = 0; mi < 2; ++mi)
#pragma unroll
            for (int ni = 0; ni < 4; ++ni) acc[mi][ni] = (f32x4){0.f, 0.f, 0.f, 0.f};

#pragma unroll 1
        for (int kt = 0; kt < 8; ++kt) {
            half8 ah[2];
#pragma unroll
            for (int mi = 0; mi < 2; ++mi)
                ah[mi] = *(const half8*)&fh[mi * 16 + lr][kt * 32 + lg * 8];
            half8 bh[4];
#pragma unroll
            for (int ni = 0; ni < 4; ++ni) {
                const float* src = W + (size_t)(w * 64 + ni * 16 + lr) * C + kt * 32 + lg * 8;
                const float4 x0 = *(const float4*)src;
                const float4 x1 = *(const float4*)(src + 4);
                bh[ni][0] = (_Float16)x0.x; bh[ni][1] = (_Float16)x0.y;
                bh[ni][2] = (_Float16)x0.z; bh[ni][3] = (_Float16)x0.w;
                bh[ni][4] = (_Float16)x1.x; bh[ni][5] = (_Float16)x1.y;
                bh[ni][6] = (_Float16)x1.z; bh[ni][7] = (_Float16)x1.w;
            }
#pragma unroll
            for (int mi = 0; mi < 2; ++mi)
#pragma unroll
                for (int ni = 0; ni < 4; ++ni)
                    acc[mi][ni] = mfma16(ah[mi], bh[ni], acc[mi][ni]);
        }
        _Float16* dst = Od[qk];
#pragma unroll
        for (int mi = 0; mi < 2; ++mi)
#pragma unroll
            for (int ni = 0; ni < 4; ++ni)
#pragma unroll
                for (int r = 0; r < 4; ++r)
                    dst[(size_t)(n0 + mi * 16 + lg * 4 + r) * C + (w * 64 + ni * 16 + lr)] =
                        (_Float16)acc[mi][ni][r];
    }

    {
        f32x4 acc[4][2];
#pragma unroll
        for (int mi = 0; mi < 4; ++mi)
#pragma unroll
            for (int ni = 0; ni < 2; ++ni) acc[mi][ni] = (f32x4){0.f, 0.f, 0.f, 0.f};

#pragma unroll 1
        for (int kt = 0; kt < 8; ++kt) {
            half8 ah[4];
#pragma unroll
            for (int mi = 0; mi < 4; ++mi) {
                const float* src = Wv + (size_t)(w * 64 + mi * 16 + lr) * C + kt * 32 + lg * 8;
                const float4 x0 = *(const float4*)src;
                const float4 x1 = *(const float4*)(src + 4);
                ah[mi][0] = (_Float16)x0.x; ah[mi][1] = (_Float16)x0.y;
                ah[mi][2] = (_Float16)x0.z; ah[mi][3] = (_Float16)x0.w;
                ah[mi][4] = (_Float16)x1.x; ah[mi][5] = (_Float16)x1.y;
                ah[mi][6] = (_Float16)x1.z; ah[mi][7] = (_Float16)x1.w;
            }
            half8 bh[2];
#pragma unroll
            for (int ni = 0; ni < 2; ++ni)
                bh[ni] = *(const half8*)&fh[ni * 16 + lr][kt * 32 + lg * 8];
#pragma unroll
            for (int mi = 0; mi < 4; ++mi)
#pragma unroll
                for (int ni = 0; ni < 2; ++ni)
                    acc[mi][ni] = mfma16(ah[mi], bh[ni], acc[mi][ni]);
        }
        _Float16* vb = Vp + (size_t)b * C * NN;
#pragma unroll
        for (int mi = 0; mi < 4; ++mi)
#pragma unroll
            for (int ni = 0; ni < 2; ++ni)
#pragma unroll
                for (int r = 0; r < 4; ++r)
                    vb[(size_t)(w * 64 + mi * 16 + lg * 4 + r) * NN + n0 + ni * 16 + lr] =
                        (_Float16)acc[mi][ni][r];
    }
}

// ---------------------------------------------------------------------------
// Kernel 2: split-K flash attention, j_wave=64, o/i-split wave pairs, i_tile=64.
// K double-buffered (prefetch spans softmax+PV), V single-buffered (load
// covered by QK), staged via global_load_lds with pre-swizzled sources.
// O master in f16. launch_bounds(512,1): LDS caps us at 1 block/CU anyway,
// so allow full register allocation -> no scratch spill (round-4 regression).
// ---------------------------------------------------------------------------
template<int KS>
__global__ __launch_bounds__(512, 1) void attn2(
    const _Float16* __restrict__ Qt, const _Float16* __restrict__ Kt,
    const _Float16* __restrict__ Vp, _Float16* __restrict__ Opart,
    float* __restrict__ ml, float* __restrict__ out)
{
    extern __shared__ char smem[];
    char* Ksh0 = smem;                                  // [64][256] f16, 512B rows
    char* Ksh1 = smem + 32768;
    char* Vsh  = smem + 65536;                          // [256][64] f16, 128B rows
    char* Psh  = smem + 98304;                          // [4][64][64] f16, 128B rows
    float* stats = (float*)(smem + 131072);             // [4][2][64]

    const int lin = blockIdx.x;
    const int xcd = lin & 7, slot = lin >> 3;
    int b, ksid, jt;
    if constexpr (KS == 4) { b = xcd >> 1; ksid = ((xcd & 1) << 1) | (slot >> 4); jt = slot & 15; }
    else                   { b = xcd >> 1; ksid = 0; jt = (slot << 1) | (xcd & 1); }

    const int tid = threadIdx.x;
    const int w = tid >> 6, lane = tid & 63;
    const int g = w >> 2, jg = w & 3;
    const int l31 = lane & 31, hi = lane >> 5, lr = lane & 15, lg = lane >> 4;
    const int j0 = jt * 256 + jg * 64;
    const int iBase = ksid * (NN / KS);
    const int T = (NN / KS) / 64;

    const _Float16* Qb = Qt + (size_t)b * NN * C;
    const char* KbC = (const char*)(Kt + (size_t)b * NN * C);
    const char* VbC = (const char*)(Vp + (size_t)b * C * NN);

    const int swzA = (l31 & 7) << 4;   // K-read / P-write rows (row&7 == l31&7)
    const int swzB = (lr & 7) << 4;    // V-read / P-read rows  (row&7 == lr&7)

    // Q fragments: 64 j-cols x C, resident (128 VGPR)
    half8 q[2][16];
#pragma unroll
    for (int jf = 0; jf < 2; ++jf)
#pragma unroll
        for (int kk = 0; kk < 16; ++kk)
            q[jf][kk] = *(const half8*)(Qb + (size_t)(j0 + jf * 32 + l31) * C + kk * 16 + hi * 8);

    // O master in f16: [of 8][jf16 4][pair 2]
    h2 Om[8][4][2];
#pragma unroll
    for (int of = 0; of < 8; ++of)
#pragma unroll
        for (int c = 0; c < 4; ++c) { Om[of][c][0] = (h2){0, 0}; Om[of][c][1] = (h2){0, 0}; }
    float mrq[2] = {-1e30f, -1e30f};
    float mrp[4] = {-1e30f, -1e30f, -1e30f, -1e30f};
    float ll[2] = {0.f, 0.f};

#define STAGE_K(dstK, t_) do {                                                 \
    const int i0_ = iBase + (t_) * 64;                                         \
    const char* ksg_ = KbC + (size_t)i0_ * 512;                                \
    _Pragma("unroll")                                                          \
    for (int r_ = 0; r_ < 4; ++r_) {                                           \
        const int p_ = r_ * 8192 + tid * 16;                                   \
        const int row_ = p_ >> 9, col_ = p_ & 511;                             \
        gld16(ksg_ + (size_t)row_ * 512 + (col_ ^ ((row_ & 7) << 4)), (dstK) + p_); \
    }                                                                          \
} while (0)

#define STAGE_V(t_) do {                                                       \
    const int i0_ = iBase + (t_) * 64;                                         \
    _Pragma("unroll")                                                          \
    for (int r_ = 0; r_ < 4; ++r_) {                                           \
        const int p_ = r_ * 8192 + tid * 16;                                   \
        const int row_ = p_ >> 7, col_ = p_ & 127;                             \
        gld16(VbC + (size_t)row_ * 8192 + (size_t)i0_ * 2 + (col_ ^ ((row_ & 7) << 4)), Vsh + p_); \
    }                                                                          \
} while (0)

    STAGE_K(Ksh0, 0);

#pragma unroll 1
    for (int t = 0; t < T; ++t) {
        __syncthreads();   // A: full drain -> K(t) staged & visible; Vsh free

        STAGE_V(t);        // V(t) in flight, covered by QK phase

        // ---- QK^T: S[i-half(g) 32, j 64] with mfma32
        const char* kb = (t & 1) ? Ksh1 : Ksh0;
        f32x16 s[2];
        s[0] = (f32x16)(0.f); s[1] = (f32x16)(0.f);
        const char* krow = kb + (size_t)(g * 32 + l31) * 512;
#pragma unroll
        for (int kk = 0; kk < 16; ++kk) {
            const half8 a = *(const half8*)(krow + ((kk * 32 + hi * 16) ^ swzA));
            s[0] = mfma32(a, q[0][kk], s[0]);
            s[1] = mfma32(a, q[1][kk], s[1]);
        }

        // ---- per-j half-max -> stats
#pragma unroll
        for (int jf = 0; jf < 2; ++jf) {
            float mh = s[jf][0];
#pragma unroll
            for (int r = 1; r < 16; ++r) mh = fmaxf(mh, s[jf][r]);
            mh = fmaxf(mh, __shfl_xor(mh, 32, 64));
            if (hi == 0) stats[(jg * 2 + g) * 64 + jf * 32 + l31] = mh;
        }
        __syncthreads();   // B: stats visible; drains V(t) (PV-safe); QK reads done

        if (t + 1 < T) {   // K(t+1) in flight, covered by softmax+PV (survives C)
            if ((t + 1) & 1) STAGE_K(Ksh1, t + 1); else STAGE_K(Ksh0, t + 1);
        }

        // ---- combine halves, unconditional rescale (P <= 1)
        float scq[2];
#pragma unroll
        for (int jf = 0; jf < 2; ++jf) {
            const int j = jf * 32 + l31;
            const float mt = fmaxf(stats[(jg * 2 + 0) * 64 + j], stats[(jg * 2 + 1) * 64 + j]);
            const float mn = fmaxf(mrq[jf], mt);
            scq[jf] = __expf(mrq[jf] - mn);
            mrq[jf] = mn;
            ll[jf] *= scq[jf];
        }
#pragma unroll
        for (int c = 0; c < 4; ++c) {
            const int j = c * 16 + lr;
            const float mt = fmaxf(stats[(jg * 2 + 0) * 64 + j], stats[(jg * 2 + 1) * 64 + j]);
            const float mn = fmaxf(mrp[c], mt);
            const float sc = __expf(mrp[c] - mn);
            mrp[c] = mn;
            const h2 s2 = {(_Float16)sc, (_Float16)sc};
#pragma unroll
            for (int of = 0; of < 8; ++of) { Om[of][c][0] *= s2; Om[of][c][1] *= s2; }
        }

        // ---- P = exp(S - m) -> Psh (f16), accumulate l
        char* pw = Psh + jg * 8192;
#pragma unroll
        for (int jf = 0; jf < 2; ++jf) {
            const int jl = jf * 32 + l31;
            float lsum = 0.f;
#pragma unroll
            for (int qc = 0; qc < 4; ++qc) {
                half4_t ph;
#pragma unroll
                for (int r = 0; r < 4; ++r) {
                    const float p = __expf(s[jf][qc * 4 + r] - mrq[jf]);
                    lsum += p;
                    ph[r] = (_Float16)p;
                }
                *(half4_t*)(pw + (size_t)jl * 128 + ((qc * 16 + hi * 8 + g * 64) ^ swzA)) = ph;
            }
            ll[jf] += lsum;
        }

        // C: raw barrier — waits LDS writes only, leaves K prefetch in flight
        asm volatile("s_waitcnt lgkmcnt(0)\n\ts_barrier" ::: "memory");
        __builtin_amdgcn_sched_barrier(0);

        // ---- PV: O[o-half(g) 128, j 64] += V P  (mfma16, k=32)
        const char* pr = Psh + jg * 8192;
#pragma unroll
        for (int kk = 0; kk < 2; ++kk) {
            half8 pb[4];
#pragma unroll
            for (int c = 0; c < 4; ++c)
                pb[c] = *(const half8*)(pr + (size_t)(c * 16 + lr) * 128 + ((kk * 64 + lg * 16) ^ swzB));
#pragma unroll
            for (int of = 0; of < 8; ++of) {
                const int vrow = g * 128 + of * 16 + lr;
                const half8 va = *(const half8*)(Vsh + (size_t)vrow * 128 + ((kk * 64 + lg * 16) ^ swzB));
#pragma unroll
                for (int c = 0; c < 4; ++c) {
                    f32x4 acc = (f32x4){0.f, 0.f, 0.f, 0.f};
                    acc = mfma16(va, pb[c], acc);
                    Om[of][c][0] += cvtpk(acc[0], acc[1]);
                    Om[of][c][1] += cvtpk(acc[2], acc[3]);
                }
            }
        }
    }

    // ---- epilogue: l exchange, normalize, write
    __syncthreads();
#pragma unroll
    for (int jf = 0; jf < 2; ++jf) {
        float lt = ll[jf] + __shfl_xor(ll[jf], 32, 64);
        if (hi == 0) stats[(jg * 2 + g) * 64 + jf * 32 + l31] = lt;
    }
    __syncthreads();

    float il[4];
#pragma unroll
    for (int c = 0; c < 4; ++c) {
        const int j = c * 16 + lr;
        const float L = stats[(jg * 2 + 0) * 64 + j] + stats[(jg * 2 + 1) * 64 + j];
        il[c] = 1.f / L;
    }

    if constexpr (KS == 4) {
        if (g == 0 && hi == 0) {
            float* mlb = ml + (size_t)(b * KS + ksid) * 2 * NN;
#pragma unroll
            for (int jf = 0; jf < 2; ++jf) {
                const int j = jf * 32 + l31;
                const float L = stats[(jg * 2 + 0) * 64 + j] + stats[(jg * 2 + 1) * 64 + j];
                mlb[j0 + j] = mrq[jf];
                mlb[NN + j0 + j] = L;
            }
        }
        _Float16* op = Opart + (size_t)(b * KS + ksid) * C * NN;
#pragma unroll
        for (int of = 0; of < 8; ++of)
#pragma unroll
            for (int c = 0; c < 4; ++c) {
                const int o0 = g * 128 + of * 16 + lg * 4;
                const int j = j0 + c * 16 + lr;
                const h2 ih = {(_Float16)il[c], (_Float16)il[c]};
                const h2 v0 = Om[of][c][0] * ih;
                const h2 v1 = Om[of][c][1] * ih;
                op[(size_t)(o0 + 0) * NN + j] = v0[0];
                op[(size_t)(o0 + 1) * NN + j] = v0[1];
                op[(size_t)(o0 + 2) * NN + j] = v1[0];
                op[(size_t)(o0 + 3) * NN + j] = v1[1];
            }
    } else {
        float* ob = out + (size_t)b * 2 * C * NN;
#pragma unroll
        for (int of = 0; of < 8; ++of)
#pragma unroll
            for (int c = 0; c < 4; ++c) {
                const int o0 = g * 128 + of * 16 + lg * 4;
                const int j = j0 + c * 16 + lr;
                ob[(size_t)(o0 + 0) * NN + j] = fmaxf((float)Om[of][c][0][0] * il[c], 0.f);
                ob[(size_t)(o0 + 1) * NN + j] = fmaxf((float)Om[of][c][0][1] * il[c], 0.f);
                ob[(size_t)(o0 + 2) * NN + j] = fmaxf((float)Om[of][c][1][0] * il[c], 0.f);
                ob[(size_t)(o0 + 3) * NN + j] = fmaxf((float)Om[of][c][1][1] * il[c], 0.f);
            }
    }
#undef STAGE_K
#undef STAGE_V
}

// ---------------------------------------------------------------------------
// Kernel 3: combine split-K partials.
// ---------------------------------------------------------------------------
template<int KS>
__global__ __launch_bounds__(256) void combine_kernel(
    const _Float16* __restrict__ Opart, const float* __restrict__ ml,
    float* __restrict__ out)
{
    const int b = blockIdx.x >> 6, cc = blockIdx.x & 63;
    const int tid = threadIdx.x;
    const int col = cc * 64 + (tid & 63);
    const int op0 = tid >> 6;
    float mv[KS], wgt[KS];
    float M = -1e30f;
#pragma unroll
    for (int s = 0; s < KS; ++s) {
        mv[s] = ml[(size_t)(b * KS + s) * 2 * NN + col];
        M = fmaxf(M, mv[s]);
    }
    float L = 0.f;
#pragma unroll
    for (int s = 0; s < KS; ++s) {
        const float lv = ml[((size_t)(b * KS + s) * 2 + 1) * NN + col];
        wgt[s] = __expf(mv[s] - M) * lv; L += wgt[s];
    }
    const float invL = 1.f / L;
#pragma unroll
    for (int s = 0; s < KS; ++s) wgt[s] *= invL;
    float* ob = out + (size_t)b * 2 * C * NN + col;
    for (int oit = 0; oit < 64; ++oit) {
        const int o = oit * 4 + op0;
        float acc = 0.f;
#pragma unroll
        for (int s = 0; s < KS; ++s)
            acc += wgt[s] * (float)Opart[((size_t)(b * KS + s) * C + o) * NN + col];
        ob[(size_t)o * NN] = fmaxf(acc, 0.f);
    }
}

// ---------------------------------------------------------------------------
extern "C" void kernel_launch(void* const* d_in, const int* in_sizes, int n_in,
                              void* d_out, int out_size, void* d_ws, size_t ws_size,
                              hipStream_t stream) {
    const float* fea = (const float*)d_in[0];
    const float* Wq  = (const float*)d_in[1];
    const float* Wk  = (const float*)d_in[2];
    const float* Wv  = (const float*)d_in[3];
    float* out = (float*)d_out;

    _Float16* Qt = (_Float16*)d_ws;
    _Float16* Kt = Qt + (size_t)NB * NN * C;
    _Float16* Vp = Kt + (size_t)NB * NN * C;
    char* extra = (char*)(Vp + (size_t)NB * NN * C);
    const size_t base = (size_t)3 * NB * NN * C * sizeof(_Float16);

    proj_kernel<<<dim3(128, 4), 256, 0, stream>>>(fea, Wq, Wk, Wv, Qt, Kt, Vp, out);

    const int SMEM = 131072 + 2048;
    const size_t need4 = base + (size_t)4 * NB * C * NN * 2 + (size_t)4 * NB * 2 * NN * 4;

    if (ws_size >= need4) {
        _Float16* Op = (_Float16*)extra;
        float* mlp = (float*)(extra + (size_t)4 * NB * C * NN * 2);
        (void)hipFuncSetAttribute(reinterpret_cast<const void*>(&attn2<4>),
                                  hipFuncAttributeMaxDynamicSharedMemorySize, SMEM);
        attn2<4><<<256, 512, SMEM, stream>>>(Qt, Kt, Vp, Op, mlp, out);
        combine_kernel<4><<<NB * 64, 256, 0, stream>>>(Op, mlp, out);
    } else {
        (void)hipFuncSetAttribute(reinterpret_cast<const void*>(&attn2<1>),
                                  hipFuncAttributeMaxDynamicSharedMemorySize, SMEM);
        attn2<1><<<64, 512, SMEM, stream>>>(Qt, Kt, Vp, nullptr, nullptr, out);
    }
}

// Round 7
// 159.052 us; speedup vs baseline: 1.6127x; 1.3590x over previous
//
#include <hip/hip_runtime.h>

#define NB 4
#define C  256
#define NN 4096

typedef _Float16 half8   __attribute__((ext_vector_type(8)));
typedef _Float16 h2      __attribute__((ext_vector_type(2)));
typedef float    f32x4   __attribute__((ext_vector_type(4)));
typedef float    f32x16  __attribute__((ext_vector_type(16)));

static __device__ __forceinline__ f32x4 mfma16(half8 a, half8 b, f32x4 c) {
    return __builtin_amdgcn_mfma_f32_16x16x32_f16(a, b, c, 0, 0, 0);
}
static __device__ __forceinline__ f32x16 mfma32(half8 a, half8 b, f32x16 c) {
    return __builtin_amdgcn_mfma_f32_32x32x16_f16(a, b, c, 0, 0, 0);
}
static __device__ __forceinline__ void gld16(const void* g, void* l) {
    __builtin_amdgcn_global_load_lds(
        (const __attribute__((address_space(1))) unsigned int*)g,
        (__attribute__((address_space(3))) unsigned int*)l, 16, 0, 0);
}
static __device__ __forceinline__ h2 cvtpk(float a, float b) {
    auto r = __builtin_amdgcn_cvt_pkrtz(a, b);
    return *reinterpret_cast<h2*>(&r);
}
static __device__ __forceinline__ unsigned cvtpk_u(float a, float b) {
    auto r = __builtin_amdgcn_cvt_pkrtz(a, b);
    return *reinterpret_cast<unsigned*>(&r);
}

// ---------------------------------------------------------------------------
// Kernel 1: QKV projection (single-f16) + relu(fea) copy to out. (unchanged)
//   Qt[b][n][t], Kt[b][n][t]  (N x 256, t contiguous)  f16
//   Vp[b][o][n]               (256 x N, n contiguous)  f16
// ---------------------------------------------------------------------------
__global__ __launch_bounds__(256) void proj_kernel(
    const float* __restrict__ fea, const float* __restrict__ Wq,
    const float* __restrict__ Wk, const float* __restrict__ Wv,
    _Float16* __restrict__ Qt, _Float16* __restrict__ Kt,
    _Float16* __restrict__ Vp, float* __restrict__ out)
{
    const int lin = blockIdx.x + gridDim.x * blockIdx.y;
    const int xcd = lin & 7;
    const int b   = xcd >> 1;
    const int nt  = ((lin >> 3) << 1) | (xcd & 1);
    const int n0  = nt * 32;

    __shared__ __align__(16) _Float16 fh[32][264];

    const int tid = threadIdx.x;
    {
        const int nl = tid & 31, rr = tid >> 5;
        const float* feab = fea + (size_t)b * C * NN + n0 + nl;
        float* outb = out + (size_t)b * 2 * C * NN + (size_t)C * NN + n0 + nl;
#pragma unroll
        for (int p = 0; p < 32; ++p) {
            const int i = p * 8 + rr;
            const float v = feab[(size_t)i * NN];
            outb[(size_t)i * NN] = fmaxf(v, 0.f);
            fh[nl][i] = (_Float16)v;
        }
    }
    __syncthreads();

    const int w = tid >> 6, lane = tid & 63, lr = lane & 15, lg = lane >> 4;

    const float* const Ws[2] = {Wq, Wk};
    _Float16* const   Od[2] = {Qt + (size_t)b * NN * C, Kt + (size_t)b * NN * C};
#pragma unroll 1
    for (int qk = 0; qk < 2; ++qk) {
        const float* __restrict__ W = Ws[qk];
        f32x4 acc[2][4];
#pragma unroll
        for (int mi = 0; mi < 2; ++mi)
#pragma unroll
            for (int ni = 0; ni < 4; ++ni) acc[mi][ni] = (f32x4){0.f, 0.f, 0.f, 0.f};

#pragma unroll 1
        for (int kt = 0; kt < 8; ++kt) {
            half8 ah[2];
#pragma unroll
            for (int mi = 0; mi < 2; ++mi)
                ah[mi] = *(const half8*)&fh[mi * 16 + lr][kt * 32 + lg * 8];
            half8 bh[4];
#pragma unroll
            for (int ni = 0; ni < 4; ++ni) {
                const float* src = W + (size_t)(w * 64 + ni * 16 + lr) * C + kt * 32 + lg * 8;
                const float4 x0 = *(const float4*)src;
                const float4 x1 = *(const float4*)(src + 4);
                bh[ni][0] = (_Float16)x0.x; bh[ni][1] = (_Float16)x0.y;
                bh[ni][2] = (_Float16)x0.z; bh[ni][3] = (_Float16)x0.w;
                bh[ni][4] = (_Float16)x1.x; bh[ni][5] = (_Float16)x1.y;
                bh[ni][6] = (_Float16)x1.z; bh[ni][7] = (_Float16)x1.w;
            }
#pragma unroll
            for (int mi = 0; mi < 2; ++mi)
#pragma unroll
                for (int ni = 0; ni < 4; ++ni)
                    acc[mi][ni] = mfma16(ah[mi], bh[ni], acc[mi][ni]);
        }
        _Float16* dst = Od[qk];
#pragma unroll
        for (int mi = 0; mi < 2; ++mi)
#pragma unroll
            for (int ni = 0; ni < 4; ++ni)
#pragma unroll
                for (int r = 0; r < 4; ++r)
                    dst[(size_t)(n0 + mi * 16 + lg * 4 + r) * C + (w * 64 + ni * 16 + lr)] =
                        (_Float16)acc[mi][ni][r];
    }

    {
        f32x4 acc[4][2];
#pragma unroll
        for (int mi = 0; mi < 4; ++mi)
#pragma unroll
            for (int ni = 0; ni < 2; ++ni) acc[mi][ni] = (f32x4){0.f, 0.f, 0.f, 0.f};

#pragma unroll 1
        for (int kt = 0; kt < 8; ++kt) {
            half8 ah[4];
#pragma unroll
            for (int mi = 0; mi < 4; ++mi) {
                const float* src = Wv + (size_t)(w * 64 + mi * 16 + lr) * C + kt * 32 + lg * 8;
                const float4 x0 = *(const float4*)src;
                const float4 x1 = *(const float4*)(src + 4);
                ah[mi][0] = (_Float16)x0.x; ah[mi][1] = (_Float16)x0.y;
                ah[mi][2] = (_Float16)x0.z; ah[mi][3] = (_Float16)x0.w;
                ah[mi][4] = (_Float16)x1.x; ah[mi][5] = (_Float16)x1.y;
                ah[mi][6] = (_Float16)x1.z; ah[mi][7] = (_Float16)x1.w;
            }
            half8 bh[2];
#pragma unroll
            for (int ni = 0; ni < 2; ++ni)
                bh[ni] = *(const half8*)&fh[ni * 16 + lr][kt * 32 + lg * 8];
#pragma unroll
            for (int mi = 0; mi < 4; ++mi)
#pragma unroll
                for (int ni = 0; ni < 2; ++ni)
                    acc[mi][ni] = mfma16(ah[mi], bh[ni], acc[mi][ni]);
        }
        _Float16* vb = Vp + (size_t)b * C * NN;
#pragma unroll
        for (int mi = 0; mi < 4; ++mi)
#pragma unroll
            for (int ni = 0; ni < 2; ++ni)
#pragma unroll
                for (int r = 0; r < 4; ++r)
                    vb[(size_t)(w * 64 + mi * 16 + lg * 4 + r) * NN + n0 + ni * 16 + lr] =
                        (_Float16)acc[mi][ni][r];
    }
}

// ---------------------------------------------------------------------------
// Kernel 2 (v3): split-K flash attention.
// 256-thread blocks (4 waves), 2 blocks/CU (LDS exactly 64KB), j_wave=32,
// i_tile=32, K+V double-buffered, ONE __syncthreads per tile.
// S, P, and O all live in lane-space j=lane&31 -> softmax fully wave-local,
// P never touches LDS (cvtpk + shfl_xor(32) register redistribution).
// K swizzle: full (row&31) XOR on 512B rows. V: 8-row 512B macro-rows.
// ---------------------------------------------------------------------------
template<int KS>
__global__ __launch_bounds__(256, 2) void attn3(
    const _Float16* __restrict__ Qt, const _Float16* __restrict__ Kt,
    const _Float16* __restrict__ Vp, _Float16* __restrict__ Opart,
    float* __restrict__ ml, float* __restrict__ out)
{
    extern __shared__ char smem[];

    const int lin = blockIdx.x;
    const int xcd = lin & 7, slot = lin >> 3;
    int b, ks, jt;
    if constexpr (KS == 4) {
        const int combo = xcd * 2 + (slot >> 5);     // 2 (b,ks) pairs per XCD
        b = combo >> 2; ks = combo & 3; jt = slot & 31;
    } else {
        b = xcd >> 1; ks = 0; jt = ((slot & 15) << 1) | (xcd & 1);
    }

    const int tid = threadIdx.x;
    const int wv = tid >> 6, lane = tid & 63;
    const int l31 = lane & 31, hi = lane >> 5;
    const int j0 = jt * 128 + wv * 32;
    const int iBase = ks * (NN / KS);
    const int T = (NN / KS) / 32;

    const _Float16* Qb = Qt + (size_t)b * NN * C;
    const char* Kg = (const char*)(Kt + (size_t)b * NN * C);
    const char* Vg = (const char*)(Vp + (size_t)b * C * NN);

    // Q fragments: wave's 32 j-cols, all C. 64 VGPR.
    half8 q[16];
#pragma unroll
    for (int kk = 0; kk < 16; ++kk)
        q[kk] = *(const half8*)(Qb + (size_t)(j0 + l31) * C + kk * 16 + hi * 8);

    // O master f16: lane j=l31; Om[ob][w] = o-pair {o,o+1}, o=(2w&3)+8*(w>>1)+4*hi+ob*32
    h2 Om[8][8];
#pragma unroll
    for (int ob = 0; ob < 8; ++ob)
#pragma unroll
        for (int w = 0; w < 8; ++w) Om[ob][w] = (h2){0, 0};
    float m = -1e30f, ll = 0.f;

    // LDS layout: K0 @0, K1 @16384, V0 @32768, V1 @49152
#define STAGE(nb, t_) do {                                                     \
    const int i0_ = iBase + (t_) * 32;                                         \
    char* dK_ = smem + ((nb) ? 16384 : 0);                                     \
    char* dV_ = smem + 32768 + ((nb) ? 16384 : 0);                             \
    _Pragma("unroll")                                                          \
    for (int r_ = 0; r_ < 4; ++r_) {                                           \
        const int p_ = r_ * 4096 + tid * 16;                                   \
        const int row_ = p_ >> 9, c1_ = (p_ >> 4) & 31;                        \
        gld16(Kg + (size_t)(i0_ + row_) * 512 + ((c1_ ^ row_) << 4), dK_ + p_);\
    }                                                                          \
    _Pragma("unroll")                                                          \
    for (int r_ = 0; r_ < 4; ++r_) {                                           \
        const int p_ = r_ * 4096 + tid * 16;                                   \
        const int mac_ = p_ >> 9, c1_ = (p_ >> 4) & 31;                        \
        const int o_ = mac_ * 8 + (c1_ >> 2);                                  \
        gld16(Vg + (size_t)o_ * (NN * 2) + (size_t)i0_ * 2 +                   \
                  (((c1_ & 3) ^ (mac_ & 3)) << 4), dV_ + p_);                  \
    }                                                                          \
} while (0)

    STAGE(0, 0);

#pragma unroll 1
    for (int t = 0; t < T; ++t) {
        __syncthreads();   // drains vmcnt: tile t staged; all reads of buf^1 done
        if (t + 1 < T) STAGE((t + 1) & 1, t + 1);   // prefetch, drained next barrier

        const char* kb = smem + ((t & 1) ? 16384 : 0);
        const char* vb = smem + 32768 + ((t & 1) ? 16384 : 0);

        // ---- QK^T: S[i 32][j 32], lane col j=l31, rows in regs
        f32x16 s = (f32x16)(0.f);
#pragma unroll
        for (int kk = 0; kk < 16; ++kk) {
            const half8 a = *(const half8*)(kb + l31 * 512 + (((kk * 2 + hi) ^ l31) << 4));
            s = mfma32(a, q[kk], s);
        }

        // ---- wave-local online softmax (lane owns column j)
        float tmax = s[0];
#pragma unroll
        for (int r = 1; r < 16; ++r) tmax = fmaxf(tmax, s[r]);
        tmax = fmaxf(tmax, __shfl_xor(tmax, 32, 64));
        const float mn = fmaxf(m, tmax);
        const float sc = __expf(m - mn);
        m = mn;
        const h2 sc2 = {(_Float16)sc, (_Float16)sc};
#pragma unroll
        for (int ob = 0; ob < 8; ++ob)
#pragma unroll
            for (int w = 0; w < 8; ++w) Om[ob][w] *= sc2;

        float p[16];
        float lsum = 0.f;
#pragma unroll
        for (int r = 0; r < 16; ++r) { p[r] = __expf(s[r] - m); lsum += p[r]; }
        ll = ll * sc + lsum;

        // ---- pack P to f16 pairs; build B-frags in regs via shfl_xor(32)
        unsigned P0 = cvtpk_u(p[0], p[1]),  P1 = cvtpk_u(p[2], p[3]);
        unsigned P2 = cvtpk_u(p[4], p[5]),  P3 = cvtpk_u(p[6], p[7]);
        unsigned P4 = cvtpk_u(p[8], p[9]),  P5 = cvtpk_u(p[10], p[11]);
        unsigned P6 = cvtpk_u(p[12], p[13]), P7 = cvtpk_u(p[14], p[15]);
        const unsigned x0 = __shfl_xor((int)P0, 32, 64), x1 = __shfl_xor((int)P1, 32, 64);
        const unsigned x2 = __shfl_xor((int)P2, 32, 64), x3 = __shfl_xor((int)P3, 32, 64);
        const unsigned x4 = __shfl_xor((int)P4, 32, 64), x5 = __shfl_xor((int)P5, 32, 64);
        const unsigned x6 = __shfl_xor((int)P6, 32, 64), x7 = __shfl_xor((int)P7, 32, 64);
        int4 fw0, fw1;
        fw0.x = hi ? x2 : P0;  fw0.y = hi ? x3 : P1;
        fw0.z = hi ? P2 : x0;  fw0.w = hi ? P3 : x1;
        fw1.x = hi ? x6 : P4;  fw1.y = hi ? x7 : P5;
        fw1.z = hi ? P6 : x4;  fw1.w = hi ? P7 : x5;
        const half8 f0 = *reinterpret_cast<half8*>(&fw0);
        const half8 f1 = *reinterpret_cast<half8*>(&fw1);

        // ---- PV: O[o 256][j 32] += V[o,i] P[i,j]; A=V frags from LDS, B=P regs
#pragma unroll
        for (int ob = 0; ob < 8; ++ob) {
            const int o = ob * 32 + l31;
            const int mac = o >> 3;
            const char* vrow = vb + mac * 512;
            const int cb = (l31 & 7) * 4;
            const int xr = l31 >> 3;  // == mac&3
            const half8 v0 = *(const half8*)(vrow + ((cb + ((0 + hi) ^ xr)) << 4));
            const half8 v1 = *(const half8*)(vrow + ((cb + ((2 + hi) ^ xr)) << 4));
            f32x16 pacc = (f32x16)(0.f);
            pacc = mfma32(v0, f0, pacc);
            pacc = mfma32(v1, f1, pacc);
#pragma unroll
            for (int w = 0; w < 8; ++w)
                Om[ob][w] += cvtpk(pacc[2 * w], pacc[2 * w + 1]);
        }
    }

    // ---- epilogue: combine hi-halves of l (m already equal), normalize, write
    const float lt = ll + __shfl_xor(ll, 32, 64);
    const float il = 1.f / lt;

    if constexpr (KS == 4) {
        if (hi == 0) {
            float* mlb = ml + (size_t)(b * KS + ks) * 2 * NN;
            mlb[j0 + l31] = m;
            mlb[NN + j0 + l31] = lt;
        }
        _Float16* op = Opart + (size_t)(b * KS + ks) * C * NN;
#pragma unroll
        for (int ob = 0; ob < 8; ++ob)
#pragma unroll
            for (int w = 0; w < 8; ++w) {
                const int o = ob * 32 + ((2 * w) & 3) + 8 * (w >> 1) + 4 * hi;
                op[(size_t)o * NN + j0 + l31]       = (_Float16)((float)Om[ob][w][0] * il);
                op[(size_t)(o + 1) * NN + j0 + l31] = (_Float16)((float)Om[ob][w][1] * il);
            }
    } else {
        float* obp = out + (size_t)b * 2 * C * NN;
#pragma unroll
        for (int ob = 0; ob < 8; ++ob)
#pragma unroll
            for (int w = 0; w < 8; ++w) {
                const int o = ob * 32 + ((2 * w) & 3) + 8 * (w >> 1) + 4 * hi;
                obp[(size_t)o * NN + j0 + l31]       = fmaxf((float)Om[ob][w][0] * il, 0.f);
                obp[(size_t)(o + 1) * NN + j0 + l31] = fmaxf((float)Om[ob][w][1] * il, 0.f);
            }
    }
#undef STAGE
}

// ---------------------------------------------------------------------------
// Kernel 3: combine split-K partials. (unchanged)
// ---------------------------------------------------------------------------
template<int KS>
__global__ __launch_bounds__(256) void combine_kernel(
    const _Float16* __restrict__ Opart, const float* __restrict__ ml,
    float* __restrict__ out)
{
    const int b = blockIdx.x >> 6, cc = blockIdx.x & 63;
    const int tid = threadIdx.x;
    const int col = cc * 64 + (tid & 63);
    const int op0 = tid >> 6;
    float mv[KS], wgt[KS];
    float M = -1e30f;
#pragma unroll
    for (int s = 0; s < KS; ++s) {
        mv[s] = ml[(size_t)(b * KS + s) * 2 * NN + col];
        M = fmaxf(M, mv[s]);
    }
    float L = 0.f;
#pragma unroll
    for (int s = 0; s < KS; ++s) {
        const float lv = ml[((size_t)(b * KS + s) * 2 + 1) * NN + col];
        wgt[s] = __expf(mv[s] - M) * lv; L += wgt[s];
    }
    const float invL = 1.f / L;
#pragma unroll
    for (int s = 0; s < KS; ++s) wgt[s] *= invL;
    float* ob = out + (size_t)b * 2 * C * NN + col;
    for (int oit = 0; oit < 64; ++oit) {
        const int o = oit * 4 + op0;
        float acc = 0.f;
#pragma unroll
        for (int s = 0; s < KS; ++s)
            acc += wgt[s] * (float)Opart[((size_t)(b * KS + s) * C + o) * NN + col];
        ob[(size_t)o * NN] = fmaxf(acc, 0.f);
    }
}

// ---------------------------------------------------------------------------
extern "C" void kernel_launch(void* const* d_in, const int* in_sizes, int n_in,
                              void* d_out, int out_size, void* d_ws, size_t ws_size,
                              hipStream_t stream) {
    const float* fea = (const float*)d_in[0];
    const float* Wq  = (const float*)d_in[1];
    const float* Wk  = (const float*)d_in[2];
    const float* Wv  = (const float*)d_in[3];
    float* out = (float*)d_out;

    _Float16* Qt = (_Float16*)d_ws;
    _Float16* Kt = Qt + (size_t)NB * NN * C;
    _Float16* Vp = Kt + (size_t)NB * NN * C;
    char* extra = (char*)(Vp + (size_t)NB * NN * C);
    const size_t base = (size_t)3 * NB * NN * C * sizeof(_Float16);

    proj_kernel<<<dim3(128, 4), 256, 0, stream>>>(fea, Wq, Wk, Wv, Qt, Kt, Vp, out);

    const int SMEM = 65536;
    const size_t need4 = base + (size_t)4 * NB * C * NN * 2 + (size_t)4 * NB * 2 * NN * 4;

    if (ws_size >= need4) {
        _Float16* Op = (_Float16*)extra;
        float* mlp = (float*)(extra + (size_t)4 * NB * C * NN * 2);
        (void)hipFuncSetAttribute(reinterpret_cast<const void*>(&attn3<4>),
                                  hipFuncAttributeMaxDynamicSharedMemorySize, SMEM);
        attn3<4><<<512, 256, SMEM, stream>>>(Qt, Kt, Vp, Op, mlp, out);
        combine_kernel<4><<<NB * 64, 256, 0, stream>>>(Op, mlp, out);
    } else {
        (void)hipFuncSetAttribute(reinterpret_cast<const void*>(&attn3<1>),
                                  hipFuncAttributeMaxDynamicSharedMemorySize, SMEM);
        attn3<1><<<128, 256, SMEM, stream>>>(Qt, Kt, Vp, nullptr, nullptr, out);
    }
}

// Round 8
// 158.247 us; speedup vs baseline: 1.6209x; 1.0051x over previous
//
#include <hip/hip_runtime.h>

#define NB 4
#define C  256
#define NN 4096

typedef _Float16 half8   __attribute__((ext_vector_type(8)));
typedef _Float16 h2      __attribute__((ext_vector_type(2)));
typedef float    f32x4   __attribute__((ext_vector_type(4)));
typedef float    f32x16  __attribute__((ext_vector_type(16)));

static __device__ __forceinline__ f32x4 mfma16(half8 a, half8 b, f32x4 c) {
    return __builtin_amdgcn_mfma_f32_16x16x32_f16(a, b, c, 0, 0, 0);
}
static __device__ __forceinline__ f32x16 mfma32(half8 a, half8 b, f32x16 c) {
    return __builtin_amdgcn_mfma_f32_32x32x16_f16(a, b, c, 0, 0, 0);
}
static __device__ __forceinline__ void gld16(const void* g, void* l) {
    __builtin_amdgcn_global_load_lds(
        (const __attribute__((address_space(1))) unsigned int*)g,
        (__attribute__((address_space(3))) unsigned int*)l, 16, 0, 0);
}
static __device__ __forceinline__ unsigned cvtpk_u(float a, float b) {
    auto r = __builtin_amdgcn_cvt_pkrtz(a, b);
    return *reinterpret_cast<unsigned*>(&r);
}

// ---------------------------------------------------------------------------
// Kernel 1: QKV projection (single-f16) + relu(fea) copy to out. (unchanged)
//   Qt[b][n][t], Kt[b][n][t]  (N x 256, t contiguous)  f16
//   Vp[b][o][n]               (256 x N, n contiguous)  f16
// ---------------------------------------------------------------------------
__global__ __launch_bounds__(256) void proj_kernel(
    const float* __restrict__ fea, const float* __restrict__ Wq,
    const float* __restrict__ Wk, const float* __restrict__ Wv,
    _Float16* __restrict__ Qt, _Float16* __restrict__ Kt,
    _Float16* __restrict__ Vp, float* __restrict__ out)
{
    const int lin = blockIdx.x + gridDim.x * blockIdx.y;
    const int xcd = lin & 7;
    const int b   = xcd >> 1;
    const int nt  = ((lin >> 3) << 1) | (xcd & 1);
    const int n0  = nt * 32;

    __shared__ __align__(16) _Float16 fh[32][264];

    const int tid = threadIdx.x;
    {
        const int nl = tid & 31, rr = tid >> 5;
        const float* feab = fea + (size_t)b * C * NN + n0 + nl;
        float* outb = out + (size_t)b * 2 * C * NN + (size_t)C * NN + n0 + nl;
#pragma unroll
        for (int p = 0; p < 32; ++p) {
            const int i = p * 8 + rr;
            const float v = feab[(size_t)i * NN];
            outb[(size_t)i * NN] = fmaxf(v, 0.f);
            fh[nl][i] = (_Float16)v;
        }
    }
    __syncthreads();

    const int w = tid >> 6, lane = tid & 63, lr = lane & 15, lg = lane >> 4;

    const float* const Ws[2] = {Wq, Wk};
    _Float16* const   Od[2] = {Qt + (size_t)b * NN * C, Kt + (size_t)b * NN * C};
#pragma unroll 1
    for (int qk = 0; qk < 2; ++qk) {
        const float* __restrict__ W = Ws[qk];
        f32x4 acc[2][4];
#pragma unroll
        for (int mi = 0; mi < 2; ++mi)
#pragma unroll
            for (int ni = 0; ni < 4; ++ni) acc[mi][ni] = (f32x4){0.f, 0.f, 0.f, 0.f};

#pragma unroll 1
        for (int kt = 0; kt < 8; ++kt) {
            half8 ah[2];
#pragma unroll
            for (int mi = 0; mi < 2; ++mi)
                ah[mi] = *(const half8*)&fh[mi * 16 + lr][kt * 32 + lg * 8];
            half8 bh[4];
#pragma unroll
            for (int ni = 0; ni < 4; ++ni) {
                const float* src = W + (size_t)(w * 64 + ni * 16 + lr) * C + kt * 32 + lg * 8;
                const float4 x0 = *(const float4*)src;
                const float4 x1 = *(const float4*)(src + 4);
                bh[ni][0] = (_Float16)x0.x; bh[ni][1] = (_Float16)x0.y;
                bh[ni][2] = (_Float16)x0.z; bh[ni][3] = (_Float16)x0.w;
                bh[ni][4] = (_Float16)x1.x; bh[ni][5] = (_Float16)x1.y;
                bh[ni][6] = (_Float16)x1.z; bh[ni][7] = (_Float16)x1.w;
            }
#pragma unroll
            for (int mi = 0; mi < 2; ++mi)
#pragma unroll
                for (int ni = 0; ni < 4; ++ni)
                    acc[mi][ni] = mfma16(ah[mi], bh[ni], acc[mi][ni]);
        }
        _Float16* dst = Od[qk];
#pragma unroll
        for (int mi = 0; mi < 2; ++mi)
#pragma unroll
            for (int ni = 0; ni < 4; ++ni)
#pragma unroll
                for (int r = 0; r < 4; ++r)
                    dst[(size_t)(n0 + mi * 16 + lg * 4 + r) * C + (w * 64 + ni * 16 + lr)] =
                        (_Float16)acc[mi][ni][r];
    }

    {
        f32x4 acc[4][2];
#pragma unroll
        for (int mi = 0; mi < 4; ++mi)
#pragma unroll
            for (int ni = 0; ni < 2; ++ni) acc[mi][ni] = (f32x4){0.f, 0.f, 0.f, 0.f};

#pragma unroll 1
        for (int kt = 0; kt < 8; ++kt) {
            half8 ah[4];
#pragma unroll
            for (int mi = 0; mi < 4; ++mi) {
                const float* src = Wv + (size_t)(w * 64 + mi * 16 + lr) * C + kt * 32 + lg * 8;
                const float4 x0 = *(const float4*)src;
                const float4 x1 = *(const float4*)(src + 4);
                ah[mi][0] = (_Float16)x0.x; ah[mi][1] = (_Float16)x0.y;
                ah[mi][2] = (_Float16)x0.z; ah[mi][3] = (_Float16)x0.w;
                ah[mi][4] = (_Float16)x1.x; ah[mi][5] = (_Float16)x1.y;
                ah[mi][6] = (_Float16)x1.z; ah[mi][7] = (_Float16)x1.w;
            }
            half8 bh[2];
#pragma unroll
            for (int ni = 0; ni < 2; ++ni)
                bh[ni] = *(const half8*)&fh[ni * 16 + lr][kt * 32 + lg * 8];
#pragma unroll
            for (int mi = 0; mi < 4; ++mi)
#pragma unroll
                for (int ni = 0; ni < 2; ++ni)
                    acc[mi][ni] = mfma16(ah[mi], bh[ni], acc[mi][ni]);
        }
        _Float16* vb = Vp + (size_t)b * C * NN;
#pragma unroll
        for (int mi = 0; mi < 4; ++mi)
#pragma unroll
            for (int ni = 0; ni < 2; ++ni)
#pragma unroll
                for (int r = 0; r < 4; ++r)
                    vb[(size_t)(w * 64 + mi * 16 + lg * 4 + r) * NN + n0 + ni * 16 + lr] =
                        (_Float16)acc[mi][ni][r];
    }
}

// ---------------------------------------------------------------------------
// Kernel 2 (v4): split-K flash attention.
// Same structure as v3 (4-wave blocks, 2/CU, one barrier/tile, reg-only P),
// but O accumulates in f32 DIRECTLY through the MFMA C operand (zero VALU
// accumulate cost) with deferred rescale (tau=8, rare after warmup).
// ---------------------------------------------------------------------------
template<int KS>
__global__ __launch_bounds__(256, 2) void attn4(
    const _Float16* __restrict__ Qt, const _Float16* __restrict__ Kt,
    const _Float16* __restrict__ Vp, _Float16* __restrict__ Opart,
    float* __restrict__ ml, float* __restrict__ out)
{
    extern __shared__ char smem[];

    const int lin = blockIdx.x;
    const int xcd = lin & 7, slot = lin >> 3;
    int b, ks, jt;
    if constexpr (KS == 4) {
        const int combo = xcd * 2 + (slot >> 5);     // 2 (b,ks) pairs per XCD
        b = combo >> 2; ks = combo & 3; jt = slot & 31;
    } else {
        b = xcd >> 1; ks = 0; jt = ((slot & 15) << 1) | (xcd & 1);
    }

    const int tid = threadIdx.x;
    const int wv = tid >> 6, lane = tid & 63;
    const int l31 = lane & 31, hi = lane >> 5;
    const int j0 = jt * 128 + wv * 32;
    const int iBase = ks * (NN / KS);
    const int T = (NN / KS) / 32;

    const _Float16* Qb = Qt + (size_t)b * NN * C;
    const char* Kg = (const char*)(Kt + (size_t)b * NN * C);
    const char* Vg = (const char*)(Vp + (size_t)b * C * NN);

    // Q fragments: wave's 32 j-cols, all C. 64 VGPR.
    half8 q[16];
#pragma unroll
    for (int kk = 0; kk < 16; ++kk)
        q[kk] = *(const half8*)(Qb + (size_t)(j0 + l31) * C + kk * 16 + hi * 8);

    // O master accumulator in f32 (128 VGPR), fed through MFMA C operand.
    f32x16 O[8];
#pragma unroll
    for (int ob = 0; ob < 8; ++ob) O[ob] = (f32x16)(0.f);
    float m = -1e30f, ll = 0.f;

    // LDS layout: K0 @0, K1 @16384, V0 @32768, V1 @49152
#define STAGE(nb, t_) do {                                                     \
    const int i0_ = iBase + (t_) * 32;                                         \
    char* dK_ = smem + ((nb) ? 16384 : 0);                                     \
    char* dV_ = smem + 32768 + ((nb) ? 16384 : 0);                             \
    _Pragma("unroll")                                                          \
    for (int r_ = 0; r_ < 4; ++r_) {                                           \
        const int p_ = r_ * 4096 + tid * 16;                                   \
        const int row_ = p_ >> 9, c1_ = (p_ >> 4) & 31;                        \
        gld16(Kg + (size_t)(i0_ + row_) * 512 + ((c1_ ^ row_) << 4), dK_ + p_);\
    }                                                                          \
    _Pragma("unroll")                                                          \
    for (int r_ = 0; r_ < 4; ++r_) {                                           \
        const int p_ = r_ * 4096 + tid * 16;                                   \
        const int mac_ = p_ >> 9, c1_ = (p_ >> 4) & 31;                        \
        const int o_ = mac_ * 8 + (c1_ >> 2);                                  \
        gld16(Vg + (size_t)o_ * (NN * 2) + (size_t)i0_ * 2 +                   \
                  (((c1_ & 3) ^ (mac_ & 3)) << 4), dV_ + p_);                  \
    }                                                                          \
} while (0)

    STAGE(0, 0);

#pragma unroll 1
    for (int t = 0; t < T; ++t) {
        __syncthreads();   // drains vmcnt: tile t staged; all reads of buf^1 done
        if (t + 1 < T) STAGE((t + 1) & 1, t + 1);   // prefetch, drained next barrier

        const char* kb = smem + ((t & 1) ? 16384 : 0);
        const char* vb = smem + 32768 + ((t & 1) ? 16384 : 0);

        // ---- QK^T: S[i 32][j 32], lane col j=l31, rows in regs
        f32x16 s = (f32x16)(0.f);
#pragma unroll
        for (int kk = 0; kk < 16; ++kk) {
            const half8 a = *(const half8*)(kb + l31 * 512 + (((kk * 2 + hi) ^ l31) << 4));
            s = mfma32(a, q[kk], s);
        }

        // ---- wave-local online softmax, deferred rescale (tau=8)
        float tmax = s[0];
#pragma unroll
        for (int r = 1; r < 16; ++r) tmax = fmaxf(tmax, s[r]);
        tmax = fmaxf(tmax, __shfl_xor(tmax, 32, 64));
        if (__any(tmax > m + 8.0f)) {
            const float mn = fmaxf(m, tmax);
            const float sc = __expf(m - mn);
            m = mn;
            ll *= sc;
#pragma unroll
            for (int ob = 0; ob < 8; ++ob) O[ob] *= sc;
        }

        float lsum = 0.f;
#pragma unroll
        for (int r = 0; r < 16; ++r) { s[r] = __expf(s[r] - m); lsum += s[r]; }
        ll += lsum;

        // ---- pack P (<= e^8, f16-safe); build B-frags in regs via shfl_xor(32)
        unsigned P0 = cvtpk_u(s[0], s[1]),   P1 = cvtpk_u(s[2], s[3]);
        unsigned P2 = cvtpk_u(s[4], s[5]),   P3 = cvtpk_u(s[6], s[7]);
        unsigned P4 = cvtpk_u(s[8], s[9]),   P5 = cvtpk_u(s[10], s[11]);
        unsigned P6 = cvtpk_u(s[12], s[13]), P7 = cvtpk_u(s[14], s[15]);
        const unsigned x0 = __shfl_xor((int)P0, 32, 64), x1 = __shfl_xor((int)P1, 32, 64);
        const unsigned x2 = __shfl_xor((int)P2, 32, 64), x3 = __shfl_xor((int)P3, 32, 64);
        const unsigned x4 = __shfl_xor((int)P4, 32, 64), x5 = __shfl_xor((int)P5, 32, 64);
        const unsigned x6 = __shfl_xor((int)P6, 32, 64), x7 = __shfl_xor((int)P7, 32, 64);
        int4 fw0, fw1;
        fw0.x = hi ? x2 : P0;  fw0.y = hi ? x3 : P1;
        fw0.z = hi ? P2 : x0;  fw0.w = hi ? P3 : x1;
        fw1.x = hi ? x6 : P4;  fw1.y = hi ? x7 : P5;
        fw1.z = hi ? P6 : x4;  fw1.w = hi ? P7 : x5;
        const half8 f0 = *reinterpret_cast<half8*>(&fw0);
        const half8 f1 = *reinterpret_cast<half8*>(&fw1);

        // ---- PV: O[o 256][j 32] += V[o,i] P[i,j]; accumulate in MFMA C (f32)
#pragma unroll
        for (int ob = 0; ob < 8; ++ob) {
            const int o = ob * 32 + l31;
            const int mac = o >> 3;
            const char* vrow = vb + mac * 512;
            const int cb = (l31 & 7) * 4;
            const int xr = l31 >> 3;  // == mac&3
            const half8 v0 = *(const half8*)(vrow + ((cb + ((0 + hi) ^ xr)) << 4));
            const half8 v1 = *(const half8*)(vrow + ((cb + ((2 + hi) ^ xr)) << 4));
            O[ob] = mfma32(v0, f0, O[ob]);
            O[ob] = mfma32(v1, f1, O[ob]);
        }
    }

    // ---- epilogue: combine hi-halves of l (m equal across halves), write
    const float lt = ll + __shfl_xor(ll, 32, 64);
    const float il = 1.f / lt;

    if constexpr (KS == 4) {
        if (hi == 0) {
            float* mlb = ml + (size_t)(b * KS + ks) * 2 * NN;
            mlb[j0 + l31] = m;
            mlb[NN + j0 + l31] = lt;
        }
        _Float16* op = Opart + (size_t)(b * KS + ks) * C * NN;
#pragma unroll
        for (int ob = 0; ob < 8; ++ob)
#pragma unroll
            for (int w = 0; w < 8; ++w) {
                const int o = ob * 32 + ((2 * w) & 3) + 8 * (w >> 1) + 4 * hi;
                op[(size_t)o * NN + j0 + l31]       = (_Float16)(O[ob][2 * w] * il);
                op[(size_t)(o + 1) * NN + j0 + l31] = (_Float16)(O[ob][2 * w + 1] * il);
            }
    } else {
        float* obp = out + (size_t)b * 2 * C * NN;
#pragma unroll
        for (int ob = 0; ob < 8; ++ob)
#pragma unroll
            for (int w = 0; w < 8; ++w) {
                const int o = ob * 32 + ((2 * w) & 3) + 8 * (w >> 1) + 4 * hi;
                obp[(size_t)o * NN + j0 + l31]       = fmaxf(O[ob][2 * w] * il, 0.f);
                obp[(size_t)(o + 1) * NN + j0 + l31] = fmaxf(O[ob][2 * w + 1] * il, 0.f);
            }
    }
#undef STAGE
}

// ---------------------------------------------------------------------------
// Kernel 3: combine split-K partials. (unchanged)
// ---------------------------------------------------------------------------
template<int KS>
__global__ __launch_bounds__(256) void combine_kernel(
    const _Float16* __restrict__ Opart, const float* __restrict__ ml,
    float* __restrict__ out)
{
    const int b = blockIdx.x >> 6, cc = blockIdx.x & 63;
    const int tid = threadIdx.x;
    const int col = cc * 64 + (tid & 63);
    const int op0 = tid >> 6;
    float mv[KS], wgt[KS];
    float M = -1e30f;
#pragma unroll
    for (int s = 0; s < KS; ++s) {
        mv[s] = ml[(size_t)(b * KS + s) * 2 * NN + col];
        M = fmaxf(M, mv[s]);
    }
    float L = 0.f;
#pragma unroll
    for (int s = 0; s < KS; ++s) {
        const float lv = ml[((size_t)(b * KS + s) * 2 + 1) * NN + col];
        wgt[s] = __expf(mv[s] - M) * lv; L += wgt[s];
    }
    const float invL = 1.f / L;
#pragma unroll
    for (int s = 0; s < KS; ++s) wgt[s] *= invL;
    float* ob = out + (size_t)b * 2 * C * NN + col;
    for (int oit = 0; oit < 64; ++oit) {
        const int o = oit * 4 + op0;
        float acc = 0.f;
#pragma unroll
        for (int s = 0; s < KS; ++s)
            acc += wgt[s] * (float)Opart[((size_t)(b * KS + s) * C + o) * NN + col];
        ob[(size_t)o * NN] = fmaxf(acc, 0.f);
    }
}

// ---------------------------------------------------------------------------
extern "C" void kernel_launch(void* const* d_in, const int* in_sizes, int n_in,
                              void* d_out, int out_size, void* d_ws, size_t ws_size,
                              hipStream_t stream) {
    const float* fea = (const float*)d_in[0];
    const float* Wq  = (const float*)d_in[1];
    const float* Wk  = (const float*)d_in[2];
    const float* Wv  = (const float*)d_in[3];
    float* out = (float*)d_out;

    _Float16* Qt = (_Float16*)d_ws;
    _Float16* Kt = Qt + (size_t)NB * NN * C;
    _Float16* Vp = Kt + (size_t)NB * NN * C;
    char* extra = (char*)(Vp + (size_t)NB * NN * C);
    const size_t base = (size_t)3 * NB * NN * C * sizeof(_Float16);

    proj_kernel<<<dim3(128, 4), 256, 0, stream>>>(fea, Wq, Wk, Wv, Qt, Kt, Vp, out);

    const int SMEM = 65536;
    const size_t need4 = base + (size_t)4 * NB * C * NN * 2 + (size_t)4 * NB * 2 * NN * 4;

    if (ws_size >= need4) {
        _Float16* Op = (_Float16*)extra;
        float* mlp = (float*)(extra + (size_t)4 * NB * C * NN * 2);
        (void)hipFuncSetAttribute(reinterpret_cast<const void*>(&attn4<4>),
                                  hipFuncAttributeMaxDynamicSharedMemorySize, SMEM);
        attn4<4><<<512, 256, SMEM, stream>>>(Qt, Kt, Vp, Op, mlp, out);
        combine_kernel<4><<<NB * 64, 256, 0, stream>>>(Op, mlp, out);
    } else {
        (void)hipFuncSetAttribute(reinterpret_cast<const void*>(&attn4<1>),
                                  hipFuncAttributeMaxDynamicSharedMemorySize, SMEM);
        attn4<1><<<128, 256, SMEM, stream>>>(Qt, Kt, Vp, nullptr, nullptr, out);
    }
}

// Round 10
// 156.935 us; speedup vs baseline: 1.6345x; 1.0084x over previous
//
#include <hip/hip_runtime.h>

#define NB 4
#define C  256
#define NN 4096

typedef _Float16 half8   __attribute__((ext_vector_type(8)));
typedef float    f32x4   __attribute__((ext_vector_type(4)));
typedef float    f32x16  __attribute__((ext_vector_type(16)));

static __device__ __forceinline__ f32x4 mfma16(half8 a, half8 b, f32x4 c) {
    return __builtin_amdgcn_mfma_f32_16x16x32_f16(a, b, c, 0, 0, 0);
}
static __device__ __forceinline__ f32x16 mfma32(half8 a, half8 b, f32x16 c) {
    return __builtin_amdgcn_mfma_f32_32x32x16_f16(a, b, c, 0, 0, 0);
}
static __device__ __forceinline__ void gld16(const void* g, void* l) {
    __builtin_amdgcn_global_load_lds(
        (const __attribute__((address_space(1))) unsigned int*)g,
        (__attribute__((address_space(3))) unsigned int*)l, 16, 0, 0);
}
static __device__ __forceinline__ unsigned cvtpk_u(float a, float b) {
    auto r = __builtin_amdgcn_cvt_pkrtz(a, b);
    return *reinterpret_cast<unsigned*>(&r);
}

// ---------------------------------------------------------------------------
// Kernel 0: one-time W (f32 -> f16) conversion. Wh = [Wq | Wk | Wv] f16.
// ---------------------------------------------------------------------------
__global__ __launch_bounds__(256) void wcvt_kernel(
    const float* __restrict__ Wq, const float* __restrict__ Wk,
    const float* __restrict__ Wv, _Float16* __restrict__ Wh)
{
    const int which = blockIdx.y;
    const float* src = which == 0 ? Wq : (which == 1 ? Wk : Wv);
    _Float16* dst = Wh + (size_t)which * (C * C);
    const int idx = blockIdx.x * 1024 + threadIdx.x * 4;
    const float4 v = *(const float4*)(src + idx);
    uint2 pk;
    pk.x = cvtpk_u(v.x, v.y);
    pk.y = cvtpk_u(v.z, v.w);
    *(uint2*)(dst + idx) = pk;
}

// ---------------------------------------------------------------------------
// Kernel 1: QKV projection (f16 W from Wh) + relu(fea) copy to out.
//   Qt[b][n][t], Kt[b][n][t]  (N x 256, t contiguous)  f16
//   Vp[b][o][n]               (256 x N, n contiguous)  f16
// ---------------------------------------------------------------------------
__global__ __launch_bounds__(256) void proj_kernel(
    const float* __restrict__ fea, const _Float16* __restrict__ Wh,
    _Float16* __restrict__ Qt, _Float16* __restrict__ Kt,
    _Float16* __restrict__ Vp, float* __restrict__ out)
{
    const int lin = blockIdx.x + gridDim.x * blockIdx.y;
    const int xcd = lin & 7;
    const int b   = xcd >> 1;
    const int nt  = ((lin >> 3) << 1) | (xcd & 1);
    const int n0  = nt * 32;

    __shared__ __align__(16) _Float16 fh[32][264];

    const int tid = threadIdx.x;
    {
        const int nl = tid & 31, rr = tid >> 5;
        const float* feab = fea + (size_t)b * C * NN + n0 + nl;
        float* outb = out + (size_t)b * 2 * C * NN + (size_t)C * NN + n0 + nl;
#pragma unroll
        for (int p = 0; p < 32; ++p) {
            const int i = p * 8 + rr;
            const float v = feab[(size_t)i * NN];
            outb[(size_t)i * NN] = fmaxf(v, 0.f);
            fh[nl][i] = (_Float16)v;
        }
    }
    __syncthreads();

    const int w = tid >> 6, lane = tid & 63, lr = lane & 15, lg = lane >> 4;

    const _Float16* const Ws[2] = {Wh, Wh + C * C};
    _Float16* const       Od[2] = {Qt + (size_t)b * NN * C, Kt + (size_t)b * NN * C};
#pragma unroll 1
    for (int qk = 0; qk < 2; ++qk) {
        const _Float16* __restrict__ W = Ws[qk];
        f32x4 acc[2][4];
#pragma unroll
        for (int mi = 0; mi < 2; ++mi)
#pragma unroll
            for (int ni = 0; ni < 4; ++ni) acc[mi][ni] = (f32x4){0.f, 0.f, 0.f, 0.f};

#pragma unroll 1
        for (int kt = 0; kt < 8; ++kt) {
            half8 ah[2];
#pragma unroll
            for (int mi = 0; mi < 2; ++mi)
                ah[mi] = *(const half8*)&fh[mi * 16 + lr][kt * 32 + lg * 8];
            half8 bh[4];
#pragma unroll
            for (int ni = 0; ni < 4; ++ni)
                bh[ni] = *(const half8*)(W + (size_t)(w * 64 + ni * 16 + lr) * C + kt * 32 + lg * 8);
#pragma unroll
            for (int mi = 0; mi < 2; ++mi)
#pragma unroll
                for (int ni = 0; ni < 4; ++ni)
                    acc[mi][ni] = mfma16(ah[mi], bh[ni], acc[mi][ni]);
        }
        _Float16* dst = Od[qk];
#pragma unroll
        for (int mi = 0; mi < 2; ++mi)
#pragma unroll
            for (int ni = 0; ni < 4; ++ni)
#pragma unroll
                for (int r = 0; r < 4; ++r)
                    dst[(size_t)(n0 + mi * 16 + lg * 4 + r) * C + (w * 64 + ni * 16 + lr)] =
                        (_Float16)acc[mi][ni][r];
    }

    {
        const _Float16* __restrict__ Wv16 = Wh + 2 * C * C;
        f32x4 acc[4][2];
#pragma unroll
        for (int mi = 0; mi < 4; ++mi)
#pragma unroll
            for (int ni = 0; ni < 2; ++ni) acc[mi][ni] = (f32x4){0.f, 0.f, 0.f, 0.f};

#pragma unroll 1
        for (int kt = 0; kt < 8; ++kt) {
            half8 ah[4];
#pragma unroll
            for (int mi = 0; mi < 4; ++mi)
                ah[mi] = *(const half8*)(Wv16 + (size_t)(w * 64 + mi * 16 + lr) * C + kt * 32 + lg * 8);
            half8 bh[2];
#pragma unroll
            for (int ni = 0; ni < 2; ++ni)
                bh[ni] = *(const half8*)&fh[ni * 16 + lr][kt * 32 + lg * 8];
#pragma unroll
            for (int mi = 0; mi < 4; ++mi)
#pragma unroll
                for (int ni = 0; ni < 2; ++ni)
                    acc[mi][ni] = mfma16(ah[mi], bh[ni], acc[mi][ni]);
        }
        _Float16* vb = Vp + (size_t)b * C * NN;
#pragma unroll
        for (int mi = 0; mi < 4; ++mi)
#pragma unroll
            for (int ni = 0; ni < 2; ++ni)
#pragma unroll
                for (int r = 0; r < 4; ++r)
                    vb[(size_t)(w * 64 + mi * 16 + lg * 4 + r) * NN + n0 + ni * 16 + lr] =
                        (_Float16)acc[mi][ni][r];
    }
}

// ---------------------------------------------------------------------------
// Kernel 2 (v6): split-K flash attention.
// = round-8 attn4 (known correct: 4-wave blocks, 2/CU, one barrier/tile,
// shfl_xor P redistribution, f32 O via MFMA C, deferred rescale tau=8)
// + split 2x8 QK chains + s_setprio around MFMA clusters.
// ---------------------------------------------------------------------------
template<int KS>
__global__ __launch_bounds__(256, 2) void attn6(
    const _Float16* __restrict__ Qt, const _Float16* __restrict__ Kt,
    const _Float16* __restrict__ Vp, _Float16* __restrict__ Opart,
    float* __restrict__ ml, float* __restrict__ out)
{
    extern __shared__ char smem[];

    const int lin = blockIdx.x;
    const int xcd = lin & 7, slot = lin >> 3;
    int b, ks, jt;
    if constexpr (KS == 4) {
        const int combo = xcd * 2 + (slot >> 5);     // 2 (b,ks) pairs per XCD
        b = combo >> 2; ks = combo & 3; jt = slot & 31;
    } else {
        b = xcd >> 1; ks = 0; jt = ((slot & 15) << 1) | (xcd & 1);
    }

    const int tid = threadIdx.x;
    const int wv = tid >> 6, lane = tid & 63;
    const int l31 = lane & 31, hi = lane >> 5;
    const int j0 = jt * 128 + wv * 32;
    const int iBase = ks * (NN / KS);
    const int T = (NN / KS) / 32;

    const _Float16* Qb = Qt + (size_t)b * NN * C;
    const char* Kg = (const char*)(Kt + (size_t)b * NN * C);
    const char* Vg = (const char*)(Vp + (size_t)b * C * NN);

    // Q fragments: wave's 32 j-cols, all C. 64 VGPR.
    half8 q[16];
#pragma unroll
    for (int kk = 0; kk < 16; ++kk)
        q[kk] = *(const half8*)(Qb + (size_t)(j0 + l31) * C + kk * 16 + hi * 8);

    // O master accumulator in f32 (128 VGPR), fed through MFMA C operand.
    f32x16 O[8];
#pragma unroll
    for (int ob = 0; ob < 8; ++ob) O[ob] = (f32x16)(0.f);
    float m = -1e30f, ll = 0.f;

    // LDS layout: K0 @0, K1 @16384, V0 @32768, V1 @49152
#define STAGE(nb, t_) do {                                                     \
    const int i0_ = iBase + (t_) * 32;                                         \
    char* dK_ = smem + ((nb) ? 16384 : 0);                                     \
    char* dV_ = smem + 32768 + ((nb) ? 16384 : 0);                             \
    _Pragma("unroll")                                                          \
    for (int r_ = 0; r_ < 4; ++r_) {                                           \
        const int p_ = r_ * 4096 + tid * 16;                                   \
        const int row_ = p_ >> 9, c1_ = (p_ >> 4) & 31;                        \
        gld16(Kg + (size_t)(i0_ + row_) * 512 + ((c1_ ^ row_) << 4), dK_ + p_);\
    }                                                                          \
    _Pragma("unroll")                                                          \
    for (int r_ = 0; r_ < 4; ++r_) {                                           \
        const int p_ = r_ * 4096 + tid * 16;                                   \
        const int mac_ = p_ >> 9, c1_ = (p_ >> 4) & 31;                        \
        const int o_ = mac_ * 8 + (c1_ >> 2);                                  \
        gld16(Vg + (size_t)o_ * (NN * 2) + (size_t)i0_ * 2 +                   \
                  (((c1_ & 3) ^ (mac_ & 3)) << 4), dV_ + p_);                  \
    }                                                                          \
} while (0)

    STAGE(0, 0);

#pragma unroll 1
    for (int t = 0; t < T; ++t) {
        __syncthreads();   // drains vmcnt: tile t staged; all reads of buf^1 done
        if (t + 1 < T) STAGE((t + 1) & 1, t + 1);   // prefetch, drained next barrier

        const char* kb = smem + ((t & 1) ? 16384 : 0);
        const char* vb = smem + 32768 + ((t & 1) ? 16384 : 0);

        // ---- QK^T: S[i 32][j 32]; two independent 8-deep MFMA chains
        f32x16 sA = (f32x16)(0.f), sB = (f32x16)(0.f);
        __builtin_amdgcn_s_setprio(1);
#pragma unroll
        for (int kk = 0; kk < 8; ++kk) {
            const half8 a0 = *(const half8*)(kb + l31 * 512 + (((kk * 2 + hi) ^ l31) << 4));
            const half8 a1 = *(const half8*)(kb + l31 * 512 + ((((kk + 8) * 2 + hi) ^ l31) << 4));
            sA = mfma32(a0, q[kk], sA);
            sB = mfma32(a1, q[kk + 8], sB);
        }
        __builtin_amdgcn_s_setprio(0);
        f32x16 s = sA + sB;

        // ---- wave-local online softmax, deferred rescale (tau=8)
        float tmax = s[0];
#pragma unroll
        for (int r = 1; r < 16; ++r) tmax = fmaxf(tmax, s[r]);
        tmax = fmaxf(tmax, __shfl_xor(tmax, 32, 64));
        if (__any(tmax > m + 8.0f)) {
            const float mn = fmaxf(m, tmax);
            const float sc = __expf(m - mn);
            m = mn;
            ll *= sc;
#pragma unroll
            for (int ob = 0; ob < 8; ++ob) O[ob] *= sc;
        }

        float lsum = 0.f;
#pragma unroll
        for (int r = 0; r < 16; ++r) { s[r] = __expf(s[r] - m); lsum += s[r]; }
        ll += lsum;

        // ---- pack P (<= e^8, f16-safe); build B-frags via shfl_xor(32) (known-good)
        unsigned P0 = cvtpk_u(s[0], s[1]),   P1 = cvtpk_u(s[2], s[3]);
        unsigned P2 = cvtpk_u(s[4], s[5]),   P3 = cvtpk_u(s[6], s[7]);
        unsigned P4 = cvtpk_u(s[8], s[9]),   P5 = cvtpk_u(s[10], s[11]);
        unsigned P6 = cvtpk_u(s[12], s[13]), P7 = cvtpk_u(s[14], s[15]);
        const unsigned x0 = __shfl_xor((int)P0, 32, 64), x1 = __shfl_xor((int)P1, 32, 64);
        const unsigned x2 = __shfl_xor((int)P2, 32, 64), x3 = __shfl_xor((int)P3, 32, 64);
        const unsigned x4 = __shfl_xor((int)P4, 32, 64), x5 = __shfl_xor((int)P5, 32, 64);
        const unsigned x6 = __shfl_xor((int)P6, 32, 64), x7 = __shfl_xor((int)P7, 32, 64);
        int4 fw0, fw1;
        fw0.x = hi ? x2 : P0;  fw0.y = hi ? x3 : P1;
        fw0.z = hi ? P2 : x0;  fw0.w = hi ? P3 : x1;
        fw1.x = hi ? x6 : P4;  fw1.y = hi ? x7 : P5;
        fw1.z = hi ? P6 : x4;  fw1.w = hi ? P7 : x5;
        const half8 f0 = *reinterpret_cast<half8*>(&fw0);
        const half8 f1 = *reinterpret_cast<half8*>(&fw1);

        // ---- PV: O[o 256][j 32] += V[o,i] P[i,j]; accumulate in MFMA C (f32)
        __builtin_amdgcn_s_setprio(1);
#pragma unroll
        for (int ob = 0; ob < 8; ++ob) {
            const int o = ob * 32 + l31;
            const int mac = o >> 3;
            const char* vrow = vb + mac * 512;
            const int cb = (l31 & 7) * 4;
            const int xr = l31 >> 3;  // == mac&3
            const half8 v0 = *(const half8*)(vrow + ((cb + ((0 + hi) ^ xr)) << 4));
            const half8 v1 = *(const half8*)(vrow + ((cb + ((2 + hi) ^ xr)) << 4));
            O[ob] = mfma32(v0, f0, O[ob]);
            O[ob] = mfma32(v1, f1, O[ob]);
        }
        __builtin_amdgcn_s_setprio(0);
    }

    // ---- epilogue: combine hi-halves of l (m equal across halves), write
    const float lt = ll + __shfl_xor(ll, 32, 64);
    const float il = 1.f / lt;

    if constexpr (KS == 4) {
        if (hi == 0) {
            float* mlb = ml + (size_t)(b * KS + ks) * 2 * NN;
            mlb[j0 + l31] = m;
            mlb[NN + j0 + l31] = lt;
        }
        _Float16* op = Opart + (size_t)(b * KS + ks) * C * NN;
#pragma unroll
        for (int ob = 0; ob < 8; ++ob)
#pragma unroll
            for (int w = 0; w < 8; ++w) {
                const int o = ob * 32 + ((2 * w) & 3) + 8 * (w >> 1) + 4 * hi;
                op[(size_t)o * NN + j0 + l31]       = (_Float16)(O[ob][2 * w] * il);
                op[(size_t)(o + 1) * NN + j0 + l31] = (_Float16)(O[ob][2 * w + 1] * il);
            }
    } else {
        float* obp = out + (size_t)b * 2 * C * NN;
#pragma unroll
        for (int ob = 0; ob < 8; ++ob)
#pragma unroll
            for (int w = 0; w < 8; ++w) {
                const int o = ob * 32 + ((2 * w) & 3) + 8 * (w >> 1) + 4 * hi;
                obp[(size_t)o * NN + j0 + l31]       = fmaxf(O[ob][2 * w] * il, 0.f);
                obp[(size_t)(o + 1) * NN + j0 + l31] = fmaxf(O[ob][2 * w + 1] * il, 0.f);
            }
    }
#undef STAGE
}

// ---------------------------------------------------------------------------
// Kernel 3: combine split-K partials. (unchanged)
// ---------------------------------------------------------------------------
template<int KS>
__global__ __launch_bounds__(256) void combine_kernel(
    const _Float16* __restrict__ Opart, const float* __restrict__ ml,
    float* __restrict__ out)
{
    const int b = blockIdx.x >> 6, cc = blockIdx.x & 63;
    const int tid = threadIdx.x;
    const int col = cc * 64 + (tid & 63);
    const int op0 = tid >> 6;
    float mv[KS], wgt[KS];
    float M = -1e30f;
#pragma unroll
    for (int s = 0; s < KS; ++s) {
        mv[s] = ml[(size_t)(b * KS + s) * 2 * NN + col];
        M = fmaxf(M, mv[s]);
    }
    float L = 0.f;
#pragma unroll
    for (int s = 0; s < KS; ++s) {
        const float lv = ml[((size_t)(b * KS + s) * 2 + 1) * NN + col];
        wgt[s] = __expf(mv[s] - M) * lv; L += wgt[s];
    }
    const float invL = 1.f / L;
#pragma unroll
    for (int s = 0; s < KS; ++s) wgt[s] *= invL;
    float* ob = out + (size_t)b * 2 * C * NN + col;
    for (int oit = 0; oit < 64; ++oit) {
        const int o = oit * 4 + op0;
        float acc = 0.f;
#pragma unroll
        for (int s = 0; s < KS; ++s)
            acc += wgt[s] * (float)Opart[((size_t)(b * KS + s) * C + o) * NN + col];
        ob[(size_t)o * NN] = fmaxf(acc, 0.f);
    }
}

// ---------------------------------------------------------------------------
extern "C" void kernel_launch(void* const* d_in, const int* in_sizes, int n_in,
                              void* d_out, int out_size, void* d_ws, size_t ws_size,
                              hipStream_t stream) {
    const float* fea = (const float*)d_in[0];
    const float* Wq  = (const float*)d_in[1];
    const float* Wk  = (const float*)d_in[2];
    const float* Wv  = (const float*)d_in[3];
    float* out = (float*)d_out;

    _Float16* Qt = (_Float16*)d_ws;
    _Float16* Kt = Qt + (size_t)NB * NN * C;
    _Float16* Vp = Kt + (size_t)NB * NN * C;
    _Float16* Wh = Vp + (size_t)NB * NN * C;          // 3 * 256*256 f16 = 384KB
    char* extra = (char*)(Wh + (size_t)3 * C * C);
    const size_t baseW = ((size_t)3 * NB * NN * C + (size_t)3 * C * C) * sizeof(_Float16);

    wcvt_kernel<<<dim3(64, 3), 256, 0, stream>>>(Wq, Wk, Wv, Wh);
    proj_kernel<<<dim3(128, 4), 256, 0, stream>>>(fea, Wh, Qt, Kt, Vp, out);

    const int SMEM = 65536;
    const size_t need4 = baseW + (size_t)4 * NB * C * NN * 2 + (size_t)4 * NB * 2 * NN * 4;

    if (ws_size >= need4) {
        _Float16* Op = (_Float16*)extra;
        float* mlp = (float*)(extra + (size_t)4 * NB * C * NN * 2);
        (void)hipFuncSetAttribute(reinterpret_cast<const void*>(&attn6<4>),
                                  hipFuncAttributeMaxDynamicSharedMemorySize, SMEM);
        attn6<4><<<512, 256, SMEM, stream>>>(Qt, Kt, Vp, Op, mlp, out);
        combine_kernel<4><<<NB * 64, 256, 0, stream>>>(Op, mlp, out);
    } else {
        (void)hipFuncSetAttribute(reinterpret_cast<const void*>(&attn6<1>),
                                  hipFuncAttributeMaxDynamicSharedMemorySize, SMEM);
        attn6<1><<<128, 256, SMEM, stream>>>(Qt, Kt, Vp, nullptr, nullptr, out);
    }
}